// Round 2
// baseline (581.745 us; speedup 1.0000x reference)
//
#include <hip/hip_runtime.h>
#include <hip/hip_bf16.h>

typedef __hip_bfloat16 bf16;
#define DEV __device__ __forceinline__

constexpr int SEQ  = 4096;
constexpr int NB   = 4;
constexpr int NTOK = NB * SEQ;          // 16384 tokens
constexpr float EPS = 1e-5f;

// ---------------- workspace layout (float offsets). Total 13914116 floats = 53.1 MiB ----------------
constexpr int OFF_WIP  = 0;                       // W_ip^T      [64][128]
constexpr int OFF_WFP  = OFF_WIP + 64 * 128;      // W_fp^T      [128][128]
constexpr int OFF_WWP  = OFF_WFP + 128 * 128;     // W_wp^T      [64][128]
constexpr int OFF_WPR  = OFF_WWP + 64 * 128;      // in_proj^T   [128][512]
constexpr int OFF_WX   = OFF_WPR + 128 * 512;     // x_proj^T    [256][40]
constexpr int OFF_WDT  = OFF_WX  + 256 * 40;      // dt_proj^T   [8][256]
constexpr int OFF_WMO  = OFF_WDT + 8 * 256;       // mamba_out^T [256][128]
constexpr int OFF_WOP  = OFF_WMO + 256 * 128;     // W_op^T      [128][64]
constexpr int OFF_XDBL = OFF_WOP + 128 * 64;      // f32 [NTOK][40]  (dt|B|C)
constexpr int OFF_U    = OFF_XDBL + NTOK * 40;    // f32 [NTOK][128]
// scratch region 1: phase1 = xn(bf16 NTOK*64) + t1(bf16 NTOK*128); phase2 = summ(f32 1M) + hin(f32 512K)
constexpr int OFF_SCR  = OFF_U + NTOK * 128;      // 1572864 floats
constexpr int OFF_SUMM = OFF_SCR;                 // f32 [64][32][256]*2... actually 64*32*256*2 = 1048576
constexpr int OFF_HIN  = OFF_SCR + 1048576;       // f32 524288
// scratch region 2: phase1 = xpre(bf16 NTOK*256); phase2 = m(f32 NTOK*128)
constexpr int OFF_B2   = OFF_SCR + 1572864;       // 2097152 floats
constexpr int OFF_WSW  = OFF_B2 + 2097152;        // bf16 NTOK*128  (1048576 floats)
constexpr int OFF_SILUZ= OFF_WSW + 1048576;       // bf16 NTOK*256  (2097152 floats)
constexpr int OFF_XC   = OFF_SILUZ + 2097152;     // bf16 NTOK*256
constexpr int OFF_G    = OFF_XC + 2097152;        // bf16 NTOK*256
constexpr int OFF_FLAG = OFF_G + 2097152;         // int dtype flag: 0 = inputs bf16, 1 = inputs f32

DEV float b2f(bf16 x) { return __bfloat162float(x); }
DEV bf16 f2b(float x) { return __float2bfloat16(x); }

// flag-selected input load: inputs may be bf16 or f32 (runtime-detected)
DEV float ldin(const void* p, int i, int f) {
  return f ? ((const float*)p)[i] : b2f(((const bf16*)p)[i]);
}

// ---------------- dtype detector ----------------
// bf16-interpretation of a true-f32 buffer: only ~53% of halfwords decode to "plausible"
// magnitudes; true-bf16 N(0,1) data decodes ~100% plausible.
__global__ void detect_k(const void* __restrict__ x, int* __restrict__ flagp) {
  __shared__ int cnt;
  if (threadIdx.x == 0) cnt = 0;
  __syncthreads();
  float v = b2f(((const bf16*)x)[threadIdx.x]);
  int ok = (v == v) && fabsf(v) > 1e-4f && fabsf(v) < 100.f;
  atomicAdd(&cnt, ok);
  __syncthreads();
  if (threadIdx.x == 0) *flagp = (cnt > 204) ? 0 : 1;
}

// ---------------- weight transpose prep ----------------
DEV void tr_one(int e, int base, int O, int I, const void* __restrict__ W,
                float* __restrict__ WT, int f) {
  int r = e - base;
  if (r >= 0 && r < O * I) {
    int o = r / I, i = r - o * I;
    WT[i * O + o] = ldin(W, r, f);
  }
}

__global__ __launch_bounds__(256) void transpose_all_k(
    const void* __restrict__ w_ip, const void* __restrict__ w_fp, const void* __restrict__ w_wp,
    const void* __restrict__ w_pr, const void* __restrict__ w_x,  const void* __restrict__ w_dt,
    const void* __restrict__ w_mo, const void* __restrict__ w_op, float* __restrict__ wsf,
    const int* __restrict__ flagp)
{
  int f = *flagp;
  int e = blockIdx.x * 256 + threadIdx.x;   // 592*256 == 151552 == total elems
  tr_one(e, OFF_WIP, 128,  64, w_ip, wsf + OFF_WIP, f);
  tr_one(e, OFF_WFP, 128, 128, w_fp, wsf + OFF_WFP, f);
  tr_one(e, OFF_WWP, 128,  64, w_wp, wsf + OFF_WWP, f);
  tr_one(e, OFF_WPR, 512, 128, w_pr, wsf + OFF_WPR, f);
  tr_one(e, OFF_WX,   40, 256, w_x,  wsf + OFF_WX, f);
  tr_one(e, OFF_WDT, 256,   8, w_dt, wsf + OFF_WDT, f);
  tr_one(e, OFF_WMO, 128, 256, w_mo, wsf + OFF_WMO, f);
  tr_one(e, OFF_WOP,  64, 128, w_op, wsf + OFF_WOP, f);
}

// ---------------- RMSNorm kernels (one wave per token) ----------------
__global__ __launch_bounds__(256) void rms1_k(const void* __restrict__ x, const void* __restrict__ w,
                                              bf16* __restrict__ xn, const int* __restrict__ flagp) {
  int f = *flagp;
  int lane = threadIdx.x & 63;
  int token = blockIdx.x * 4 + (threadIdx.x >> 6);
  float v = ldin(x, token * 64 + lane, f);
  float ss = v * v;
  #pragma unroll
  for (int m = 32; m >= 1; m >>= 1) ss += __shfl_xor(ss, m, 64);
  float sc = rsqrtf(ss * (1.f / 64.f) + EPS);
  xn[token * 64 + lane] = f2b(v * sc * ldin(w, lane, f));
}

// m <- rmsnorm(m)*w2 + u   (in-place, f32)
__global__ __launch_bounds__(256) void rms2_add_k(float* __restrict__ m, const void* __restrict__ w2,
                                                  const float* __restrict__ u, const int* __restrict__ flagp) {
  int f = *flagp;
  int lane = threadIdx.x & 63;
  int token = blockIdx.x * 4 + (threadIdx.x >> 6);
  float v0 = m[token * 128 + lane], v1 = m[token * 128 + 64 + lane];
  float ss = v0 * v0 + v1 * v1;
  #pragma unroll
  for (int mm = 32; mm >= 1; mm >>= 1) ss += __shfl_xor(ss, mm, 64);
  float sc = rsqrtf(ss * (1.f / 128.f) + EPS);
  m[token * 128 + lane]      = v0 * sc * ldin(w2, lane, f)      + u[token * 128 + lane];
  m[token * 128 + 64 + lane] = v1 * sc * ldin(w2, 64 + lane, f) + u[token * 128 + 64 + lane];
}

// ---------------- causal depthwise conv (width 4) + silu ----------------
__global__ __launch_bounds__(256) void conv_k(const bf16* __restrict__ xpre, const void* __restrict__ cw,
                                              const void* __restrict__ cb, bf16* __restrict__ xc,
                                              const int* __restrict__ flagp) {
  int f = *flagp;
  int tok = blockIdx.x;
  int ch = threadIdx.x;
  int l = tok & (SEQ - 1);
  float acc = ldin(cb, ch, f);
  #pragma unroll
  for (int k = 0; k < 4; ++k) {
    int off = k - 3;
    if (l + off >= 0) acc += b2f(xpre[(tok + off) * 256 + ch]) * ldin(cw, ch * 4 + k, f);
  }
  xc[tok * 256 + ch] = f2b(acc / (1.f + __expf(-acc)));   // silu
}

// ---------------- generic register-blocked matvec over tokens ----------------
enum { EPI_PLAIN = 0, EPI_SWISH = 1, EPI_SOFTPLUS = 2, EPI_FINAL = 3 };

template<int I, int TB, int OG, int R_O, int O_REAL, int EPI, bool IN_BF, bool HAS_IN2, bool OUT_BF>
__global__ __launch_bounds__(256) void matvec_k(
    const void* __restrict__ in_v, const float* __restrict__ in2,
    const float* __restrict__ Wt, int w_stride, int in_stride, int out_stride,
    const void* __restrict__ bias, void* __restrict__ out_v,
    const void* __restrict__ resid, const int* __restrict__ flagp)
{
  constexpr int OC = OG * R_O;
  constexpr int IN_LDS = TB * (I + 1);
  constexpr int OUT_LDS = TB * (OC + 1);
  __shared__ float lds[(IN_LDS > OUT_LDS) ? IN_LDS : OUT_LDS];

  const int f = *flagp;
  const int tid = threadIdx.x;
  const int tok0 = blockIdx.x * TB;
  const int o_base = blockIdx.y * OC;
  const int tok = tid % TB;
  const int og = tid / TB;

  // stage inputs (coalesced global -> LDS, f32, stride padded +1)
  for (int e = tid; e < TB * I; e += 256) {
    int t = e / I, i = e - t * I;
    float v;
    if (IN_BF) v = b2f(((const bf16*)in_v)[(tok0 + t) * in_stride + i]);
    else       v = ((const float*)in_v)[(tok0 + t) * in_stride + i];
    if (HAS_IN2) v *= in2[(tok0 + t) * in_stride + i];
    lds[t * (I + 1) + i] = v;
  }
  __syncthreads();

  float acc[R_O];
  #pragma unroll
  for (int r = 0; r < R_O; ++r) acc[r] = 0.f;

  const float* __restrict__ wp = Wt + o_base + og * R_O;
  const float* __restrict__ inp = lds + tok * (I + 1);
  #pragma unroll 4
  for (int i = 0; i < I; ++i) {
    float xin = inp[i];
    const float* wr = wp + i * w_stride;
    #pragma unroll
    for (int r4 = 0; r4 < R_O / 4; ++r4) {
      float4 w = *(const float4*)(wr + r4 * 4);
      acc[r4 * 4 + 0] = fmaf(xin, w.x, acc[r4 * 4 + 0]);
      acc[r4 * 4 + 1] = fmaf(xin, w.y, acc[r4 * 4 + 1]);
      acc[r4 * 4 + 2] = fmaf(xin, w.z, acc[r4 * 4 + 2]);
      acc[r4 * 4 + 3] = fmaf(xin, w.w, acc[r4 * 4 + 3]);
    }
  }
  __syncthreads();   // done with in-LDS; reuse as out staging

  #pragma unroll
  for (int r = 0; r < R_O; ++r) {
    int o = og * R_O + r;
    if (O_REAL < OC && o >= O_REAL) continue;   // x_proj O=40 pad guard
    float v = acc[r];
    if (bias) v += ldin(bias, o_base + o, f);
    if (EPI == EPI_SWISH) v = v / (1.f + __expf(-v));
    lds[tok * (OC + 1) + o] = v;
  }
  __syncthreads();

  for (int e = tid; e < TB * O_REAL; e += 256) {
    int t = e / O_REAL, o = e - t * O_REAL;
    float v = lds[t * (OC + 1) + o];
    int gaddr = (tok0 + t) * out_stride + o_base + o;
    if (EPI == EPI_FINAL) {
      v += ldin(resid, gaddr, f);
      if (f) ((float*)out_v)[gaddr] = v;
      else   ((bf16*)out_v)[gaddr] = f2b(v);
    } else if (OUT_BF) {
      ((bf16*)out_v)[gaddr] = f2b(v);
    } else {
      ((float*)out_v)[gaddr] = v;
    }
  }
}

// ---------------- chunked selective scan (delta fused in) ----------------
// grid.x = b*16+dg (64), grid.y = chunk c (32).  block 256 = 16 d-channels x 16 states.
// phase A (!IS_C): per-chunk summary (aP = prod dA, hP = chunk-local h from h0=0)
// phase C ( IS_C): replay chunk from hinit, emit gated y (bf16) into g.
template<bool IS_C>
__global__ __launch_bounds__(256) void scan_k(
    const float* __restrict__ xdbl, const bf16* __restrict__ xc, const bf16* __restrict__ siluz,
    const void* __restrict__ A_log, const void* __restrict__ D_par, const void* __restrict__ dt_b,
    const float* __restrict__ WDT, float* __restrict__ summ, const float* __restrict__ hinit,
    bf16* __restrict__ g, const int* __restrict__ flagp)
{
  const int f = *flagp;
  const int tid = threadIdx.x;
  const int bb = blockIdx.x >> 4, dg = blockIdx.x & 15, c = blockIdx.y;
  const int dl = tid >> 4, s = tid & 15;         // t-loop channel dl, state s
  const int j = tid & 15;                        // staging channel (j == s slot, reused)
  const int d_loop = dg * 16 + dl;
  const int d_stg  = dg * 16 + j;
  const int tok_base = bb * SEQ + c * 128;

  __shared__ float dt_l[64 * 8];        // dt per token
  __shared__ float dx_l[64 * 16 * 2];   // (delta, xc) interleaved
  __shared__ float bc_l[64 * 16 * 2];   // (B, C) interleaved
  __shared__ float sz_l[64 * 16];       // silu(z) (phase C)
  __shared__ float g_l[64 * 16];        // output staging (phase C)

  const float Aval = -__expf(ldin(A_log, d_loop * 16 + s, f));
  const float Dp = ldin(D_par, d_loop, f);
  const float dtb_j = ldin(dt_b, d_stg, f);
  float wdt[8];
  #pragma unroll
  for (int r = 0; r < 8; ++r) wdt[r] = WDT[r * 256 + d_stg];  // per-thread dt_proj column

  const int sidx = (blockIdx.x * 32 + c) * 256 + tid;
  float h = IS_C ? hinit[sidx] : 0.f;
  float aP = 1.f;

  for (int sub = 0; sub < 2; ++sub) {
    const int t0 = tok_base + sub * 64;
    __syncthreads();
    for (int e2 = tid; e2 < 64 * 8; e2 += 256) {
      dt_l[e2] = xdbl[(t0 + (e2 >> 3)) * 40 + (e2 & 7)];
    }
    for (int k = 0; k < 4; ++k) {
      int e = tid + k * 256;            // e = t*16 + j  (j fixed per thread)
      int t = e >> 4;
      int tok = t0 + t;
      dx_l[e * 2 + 1] = b2f(xc[tok * 256 + d_stg]);
      bc_l[e * 2 + 0] = xdbl[tok * 40 + 8 + j];    // B
      bc_l[e * 2 + 1] = xdbl[tok * 40 + 24 + j];   // C
      if (IS_C) sz_l[e] = b2f(siluz[tok * 256 + d_stg]);
    }
    __syncthreads();
    // delta = softplus(dt @ dt_proj^T + bias) computed in-LDS
    for (int k = 0; k < 4; ++k) {
      int e = tid + k * 256;
      int t = e >> 4;
      float a = dtb_j;
      #pragma unroll
      for (int r = 0; r < 8; ++r) a = fmaf(dt_l[t * 8 + r], wdt[r], a);
      dx_l[e * 2 + 0] = (a > 20.f) ? a : log1pf(__expf(a));
    }
    __syncthreads();
    #pragma unroll 4
    for (int t = 0; t < 64; ++t) {
      float dlt = dx_l[(t * 16 + dl) * 2 + 0];
      float xcv = dx_l[(t * 16 + dl) * 2 + 1];
      float dA = __expf(dlt * Aval);
      float du = dlt * xcv;
      if (!IS_C) aP *= dA;
      h = fmaf(dA, h, du * bc_l[(t * 16 + s) * 2 + 0]);
      if (IS_C) {
        float p = h * bc_l[(t * 16 + s) * 2 + 1];
        p += __shfl_xor(p, 1, 16);
        p += __shfl_xor(p, 2, 16);
        p += __shfl_xor(p, 4, 16);
        p += __shfl_xor(p, 8, 16);   // all 16 lanes hold sum_s
        if (s == 0) g_l[t * 16 + dl] = (p + xcv * Dp) * sz_l[t * 16 + dl];
      }
    }
    if (IS_C) {
      __syncthreads();
      for (int k = 0; k < 4; ++k) {
        int e = tid + k * 256;
        int t = e >> 4;
        g[(t0 + t) * 256 + d_stg] = f2b(g_l[e]);
      }
    }
  }
  if (!IS_C) { summ[sidx * 2 + 0] = aP; summ[sidx * 2 + 1] = h; }
}

// phase B: exclusive scan over the 32 chunk summaries per (b,d,s)
__global__ __launch_bounds__(256) void scanB_k(const float* __restrict__ summ, float* __restrict__ hinit) {
  int e = blockIdx.x * 256 + threadIdx.x;   // 64*256 = 16384 sequences
  int b16dg = e >> 8, q = e & 255;
  float h = 0.f;
  for (int c = 0; c < 32; ++c) {
    int idx = (b16dg * 32 + c) * 256 + q;
    hinit[idx] = h;
    h = summ[idx * 2 + 0] * h + summ[idx * 2 + 1];
  }
}

// ---------------- launch ----------------
extern "C" void kernel_launch(void* const* d_in, const int* in_sizes, int n_in,
                              void* d_out, int out_size, void* d_ws, size_t ws_size,
                              hipStream_t stream) {
  (void)in_sizes; (void)n_in; (void)out_size; (void)ws_size;
  const void* x        = d_in[0];
  const void* w_norm1  = d_in[1];
  const void* w_norm2  = d_in[2];
  const void* W_ip     = d_in[3];
  const void* b_ip     = d_in[4];
  const void* W_fp     = d_in[5];
  const void* b_fp     = d_in[6];
  const void* W_wp     = d_in[7];
  const void* b_wp     = d_in[8];
  const void* W_op     = d_in[9];
  const void* b_op     = d_in[10];
  const void* in_proj  = d_in[11];
  const void* conv_w   = d_in[12];
  const void* conv_b   = d_in[13];
  const void* x_proj   = d_in[14];
  const void* dt_projw = d_in[15];
  const void* dt_projb = d_in[16];
  const void* A_log    = d_in[17];
  const void* D_par    = d_in[18];
  const void* mo_w     = d_in[19];

  float* wsf  = (float*)d_ws;
  float* xdbl = wsf + OFF_XDBL;
  float* u_f  = wsf + OFF_U;
  float* summ = wsf + OFF_SUMM;
  float* hin  = wsf + OFF_HIN;
  float* m_f  = wsf + OFF_B2;
  bf16* xn_b   = (bf16*)(wsf + OFF_SCR);
  bf16* t1_b   = (bf16*)(wsf + OFF_SCR + NTOK * 64 / 2);
  bf16* xpre_b = (bf16*)(wsf + OFF_B2);
  bf16* wsw_b  = (bf16*)(wsf + OFF_WSW);
  bf16* siluz_b= (bf16*)(wsf + OFF_SILUZ);
  bf16* xc_b   = (bf16*)(wsf + OFF_XC);
  bf16* g_b    = (bf16*)(wsf + OFF_G);
  int*  flagp  = (int*)(wsf + OFF_FLAG);

  // -1) detect input dtype (bf16 vs f32)
  detect_k<<<dim3(1), dim3(256), 0, stream>>>(x, flagp);
  // 0) transpose all weights -> f32 WT in ws
  transpose_all_k<<<dim3(592), dim3(256), 0, stream>>>(W_ip, W_fp, W_wp, in_proj, x_proj,
                                                       dt_projw, mo_w, W_op, wsf, flagp);
  // 1) rmsnorm1
  rms1_k<<<dim3(NTOK / 4), dim3(256), 0, stream>>>(x, w_norm1, xn_b, flagp);
  // 2) t1 = W_ip@xn + b_ip
  matvec_k<64, 32, 8, 16, 128, EPI_PLAIN, true, false, true>
      <<<dim3(NTOK / 32, 1), dim3(256), 0, stream>>>(xn_b, nullptr, wsf + OFF_WIP, 128, 64, 128, b_ip, t1_b, nullptr, flagp);
  // 3) wsw = swish(W_wp@xn + b_wp)
  matvec_k<64, 32, 8, 16, 128, EPI_SWISH, true, false, true>
      <<<dim3(NTOK / 32, 1), dim3(256), 0, stream>>>(xn_b, nullptr, wsf + OFF_WWP, 128, 64, 128, b_wp, wsw_b, nullptr, flagp);
  // 4) u = W_fp@t1 + b_fp  (f32)
  matvec_k<128, 32, 8, 16, 128, EPI_PLAIN, true, false, false>
      <<<dim3(NTOK / 32, 1), dim3(256), 0, stream>>>(t1_b, nullptr, wsf + OFF_WFP, 128, 128, 128, b_fp, u_f, nullptr, flagp);
  // 5) xpre = in_proj[0:256]@u ; 6) siluz = silu(in_proj[256:512]@u)
  matvec_k<128, 32, 8, 16, 128, EPI_PLAIN, false, false, true>
      <<<dim3(NTOK / 32, 2), dim3(256), 0, stream>>>(u_f, nullptr, wsf + OFF_WPR, 512, 128, 256, nullptr, xpre_b, nullptr, flagp);
  matvec_k<128, 32, 8, 16, 128, EPI_SWISH, false, false, true>
      <<<dim3(NTOK / 32, 2), dim3(256), 0, stream>>>(u_f, nullptr, wsf + OFF_WPR + 256, 512, 128, 256, nullptr, siluz_b, nullptr, flagp);
  // 7) causal depthwise conv + silu
  conv_k<<<dim3(NTOK), dim3(256), 0, stream>>>(xpre_b, conv_w, conv_b, xc_b, flagp);
  // 8) xdbl = x_proj@xc   (O=40, padded to 64 with guard)
  matvec_k<256, 16, 16, 4, 40, EPI_PLAIN, true, false, false>
      <<<dim3(NTOK / 16, 1), dim3(256), 0, stream>>>(xc_b, nullptr, wsf + OFF_WX, 40, 256, 40, nullptr, xdbl, nullptr, flagp);
  // 9) scan: chunk summaries -> chunk-boundary states -> replay with output (delta fused)
  scan_k<false><<<dim3(64, 32), dim3(256), 0, stream>>>(xdbl, xc_b, siluz_b, A_log, D_par, dt_projb,
                                                        wsf + OFF_WDT, summ, hin, g_b, flagp);
  scanB_k<<<dim3(64), dim3(256), 0, stream>>>(summ, hin);
  scan_k<true><<<dim3(64, 32), dim3(256), 0, stream>>>(xdbl, xc_b, siluz_b, A_log, D_par, dt_projb,
                                                       wsf + OFF_WDT, summ, hin, g_b, flagp);
  // 10) m = mamba_out@g  (f32)
  matvec_k<256, 16, 16, 8, 128, EPI_PLAIN, true, false, false>
      <<<dim3(NTOK / 16, 1), dim3(256), 0, stream>>>(g_b, nullptr, wsf + OFF_WMO, 128, 256, 128, nullptr, m_f, nullptr, flagp);
  // 11) m = rmsnorm(m)*w2 + u
  rms2_add_k<<<dim3(NTOK / 4), dim3(256), 0, stream>>>(m_f, w_norm2, u_f, flagp);
  // 12) out = W_op@(wsw * m) + b_op + x
  matvec_k<128, 32, 8, 8, 64, EPI_FINAL, true, true, true>
      <<<dim3(NTOK / 32, 1), dim3(256), 0, stream>>>(wsw_b, m_f, wsf + OFF_WOP, 64, 128, 64, b_op, d_out, x, flagp);
}

// Round 3
// 527.752 us; speedup vs baseline: 1.1023x; 1.1023x over previous
//
#include <hip/hip_runtime.h>
#include <hip/hip_bf16.h>

typedef __hip_bfloat16 bf16;
#define DEV __device__ __forceinline__

constexpr int SEQ  = 4096;
constexpr int NB   = 4;
constexpr int NTOK = NB * SEQ;          // 16384 tokens
constexpr float EPS = 1e-5f;
constexpr int NCH = 64;                 // scan chunk length (tokens)
constexpr int NCHUNK = SEQ / NCH;       // 64 chunks per sequence

// ---------------- workspace layout (float offsets) — 49.4 MB total ----------------
constexpr int OFF_WIP  = 0;                        // W_ip^T      [64][128]
constexpr int OFF_WFP  = OFF_WIP + 64 * 128;       // W_fp^T      [128][128]
constexpr int OFF_WWP  = OFF_WFP + 128 * 128;      // W_wp^T      [64][128]
constexpr int OFF_WPR  = OFF_WWP + 64 * 128;       // in_proj^T   [128][512]
constexpr int OFF_WX   = OFF_WPR + 128 * 512;      // x_proj^T    [256][40]
constexpr int OFF_WDT  = OFF_WX  + 256 * 40;       // dt_proj^T   [8][256]
constexpr int OFF_WMO  = OFF_WDT + 8 * 256;        // mamba_out^T [256][128]
constexpr int OFF_WOP  = OFF_WMO + 256 * 128;      // W_op^T      [128][64]
constexpr int OFF_XDBL = OFF_WOP + 128 * 64;       // f32 [NTOK][40]  (dt|B|C)
constexpr int OFF_U    = OFF_XDBL + NTOK * 40;     // bf16 [NTOK][128]   (1048576 f)
constexpr int OFF_WSW  = OFF_U    + 1048576;       // bf16 [NTOK][128]
constexpr int OFF_SILUZ= OFF_WSW  + 1048576;       // bf16 [NTOK][256]   (2097152 f)
constexpr int OFF_XC   = OFF_SILUZ+ 2097152;       // bf16 [NTOK][256]
constexpr int OFF_G    = OFF_XC   + 2097152;       // bf16 [NTOK][256]
constexpr int OFF_R1   = OFF_G    + 2097152;       // t1(bf16 NTOK*128) then hinit(f32 1048576)
constexpr int OFF_R2   = OFF_R1   + 1048576;       // xpre(bf16 NTOK*256) then summ(f32 2097152)
constexpr int OFF_FLAG = OFF_R2   + 2097152;       // int dtype flag

DEV float b2f(bf16 x) { return __bfloat162float(x); }
DEV bf16 f2b(float x) { return __float2bfloat16(x); }
DEV float ldin(const void* p, int i, int f) {
  return f ? ((const float*)p)[i] : b2f(((const bf16*)p)[i]);
}
DEV unsigned pack2(float a, float b) {   // two bf16 -> u32
  bf16 ha = f2b(a), hb = f2b(b);
  unsigned short ua, ub;
  __builtin_memcpy(&ua, &ha, 2); __builtin_memcpy(&ub, &hb, 2);
  return (unsigned)ua | ((unsigned)ub << 16);
}
template<int CTRL>
DEV float dpp_add(float v) {   // v + row_ror:N(v) within 16-lane rows — VALU pipe
  int r = __builtin_amdgcn_update_dpp(0, __float_as_int(v), CTRL, 0xF, 0xF, false);
  return v + __int_as_float(r);
}
DEV float softplus(float a) { return (a > 20.f) ? a : log1pf(__expf(a)); }
DEV float silu(float a) { return a / (1.f + __expf(-a)); }

// ---------------- dtype detector (unchanged — validated in R2) ----------------
__global__ void detect_k(const void* __restrict__ x, int* __restrict__ flagp) {
  __shared__ int cnt;
  if (threadIdx.x == 0) cnt = 0;
  __syncthreads();
  float v = b2f(((const bf16*)x)[threadIdx.x]);
  int ok = (v == v) && fabsf(v) > 1e-4f && fabsf(v) < 100.f;
  atomicAdd(&cnt, ok);
  __syncthreads();
  if (threadIdx.x == 0) *flagp = (cnt > 204) ? 0 : 1;
}

// ---------------- weight transpose prep ----------------
DEV void tr_one(int e, int base, int O, int I, const void* __restrict__ W,
                float* __restrict__ WT, int f) {
  int r = e - base;
  if (r >= 0 && r < O * I) {
    int o = r / I, i = r - o * I;
    WT[i * O + o] = ldin(W, r, f);
  }
}
__global__ __launch_bounds__(256) void transpose_all_k(
    const void* __restrict__ w_ip, const void* __restrict__ w_fp, const void* __restrict__ w_wp,
    const void* __restrict__ w_pr, const void* __restrict__ w_x,  const void* __restrict__ w_dt,
    const void* __restrict__ w_mo, const void* __restrict__ w_op, float* __restrict__ wsf,
    const int* __restrict__ flagp)
{
  int f = *flagp;
  int e = blockIdx.x * 256 + threadIdx.x;
  tr_one(e, OFF_WIP, 128,  64, w_ip, wsf + OFF_WIP, f);
  tr_one(e, OFF_WFP, 128, 128, w_fp, wsf + OFF_WFP, f);
  tr_one(e, OFF_WWP, 128,  64, w_wp, wsf + OFF_WWP, f);
  tr_one(e, OFF_WPR, 512, 128, w_pr, wsf + OFF_WPR, f);
  tr_one(e, OFF_WX,   40, 256, w_x,  wsf + OFF_WX, f);
  tr_one(e, OFF_WDT, 256,   8, w_dt, wsf + OFF_WDT, f);
  tr_one(e, OFF_WMO, 128, 256, w_mo, wsf + OFF_WMO, f);
  tr_one(e, OFF_WOP,  64, 128, w_op, wsf + OFF_WOP, f);
}

// ---------------- front: rms1 + W_ip -> t1, W_wp -> wsw ----------------
// block: 32 tokens, 256 thr = 32 tok x 8 og; og covers 16 outs of each head
__global__ __launch_bounds__(256) void front_k(
    const void* __restrict__ x, const void* __restrict__ w1,
    const float* __restrict__ WIP, const float* __restrict__ WWP,
    const void* __restrict__ b_ip, const void* __restrict__ b_wp,
    bf16* __restrict__ t1, bf16* __restrict__ wsw, const int* __restrict__ flagp)
{
  __shared__ float xs[32 * 65];
  const int f = *flagp;
  const int tid = threadIdx.x;
  const int tok0 = blockIdx.x * 32;
  for (int e = tid; e < 32 * 64; e += 256) {
    int t = e >> 6, i = e & 63;
    xs[t * 65 + i] = ldin(x, (tok0 + t) * 64 + i, f);
  }
  __syncthreads();
  {  // rms: tid = tok*8 + r (8 lanes per token, consecutive)
    int tok = tid >> 3, r = tid & 7;
    float ss = 0.f;
    #pragma unroll
    for (int k = 0; k < 8; ++k) { float v = xs[tok * 65 + r * 8 + k]; ss += v * v; }
    ss += __shfl_xor(ss, 1, 8); ss += __shfl_xor(ss, 2, 8); ss += __shfl_xor(ss, 4, 8);
    float sc = rsqrtf(ss * (1.f / 64.f) + EPS);
    #pragma unroll
    for (int k = 0; k < 8; ++k) {
      int i = r * 8 + k;
      xs[tok * 65 + i] = xs[tok * 65 + i] * sc * ldin(w1, i, f);
    }
  }
  __syncthreads();
  const int tok = tid & 31, og = tid >> 5;     // 8 og-groups x 16 outs
  float a1[16], a2[16];
  #pragma unroll
  for (int r = 0; r < 16; ++r) { a1[r] = 0.f; a2[r] = 0.f; }
  const float* in = xs + tok * 65;
  const float* w1p = WIP + og * 16;
  const float* w2p = WWP + og * 16;
  #pragma unroll 2
  for (int i = 0; i < 64; ++i) {
    float xv = in[i];
    #pragma unroll
    for (int q = 0; q < 4; ++q) {
      float4 wa = *(const float4*)(w1p + i * 128 + q * 4);
      float4 wb = *(const float4*)(w2p + i * 128 + q * 4);
      a1[q*4+0] = fmaf(xv, wa.x, a1[q*4+0]); a1[q*4+1] = fmaf(xv, wa.y, a1[q*4+1]);
      a1[q*4+2] = fmaf(xv, wa.z, a1[q*4+2]); a1[q*4+3] = fmaf(xv, wa.w, a1[q*4+3]);
      a2[q*4+0] = fmaf(xv, wb.x, a2[q*4+0]); a2[q*4+1] = fmaf(xv, wb.y, a2[q*4+1]);
      a2[q*4+2] = fmaf(xv, wb.z, a2[q*4+2]); a2[q*4+3] = fmaf(xv, wb.w, a2[q*4+3]);
    }
  }
  unsigned p1[8], p2[8];
  #pragma unroll
  for (int q = 0; q < 8; ++q) {
    int o0 = og * 16 + q * 2;
    float v0 = a1[q*2] + ldin(b_ip, o0, f), v1 = a1[q*2+1] + ldin(b_ip, o0+1, f);
    p1[q] = pack2(v0, v1);
    float u0 = a2[q*2] + ldin(b_wp, o0, f), u1 = a2[q*2+1] + ldin(b_wp, o0+1, f);
    p2[q] = pack2(silu(u0), silu(u1));
  }
  uint4* d1 = (uint4*)(t1 + (tok0 + tok) * 128 + og * 16);
  d1[0] = make_uint4(p1[0],p1[1],p1[2],p1[3]); d1[1] = make_uint4(p1[4],p1[5],p1[6],p1[7]);
  uint4* d2 = (uint4*)(wsw + (tok0 + tok) * 128 + og * 16);
  d2[0] = make_uint4(p2[0],p2[1],p2[2],p2[3]); d2[1] = make_uint4(p2[4],p2[5],p2[6],p2[7]);
}

// ---------------- mid: u = W_fp@t1 + b_fp ; then in_proj half -> xpre / siluz ----------------
// grid (NTOK/32, 2); y picks in_proj half (y==0 also writes u)
__global__ __launch_bounds__(256) void mid_k(
    const bf16* __restrict__ t1, const float* __restrict__ WFP, const void* __restrict__ b_fp,
    const float* __restrict__ WPR, bf16* __restrict__ u_out,
    bf16* __restrict__ xpre, bf16* __restrict__ siluz, const int* __restrict__ flagp)
{
  __shared__ float s1[32 * 129];
  __shared__ float s2[32 * 129];
  const int f = *flagp;
  const int tid = threadIdx.x;
  const int tok0 = blockIdx.x * 32;
  const int half = blockIdx.y;
  for (int e = tid; e < 32 * 128; e += 256) {
    int t = e >> 7, i = e & 127;
    s1[t * 129 + i] = b2f(t1[(tok0 + t) * 128 + i]);
  }
  __syncthreads();
  const int tok = tid & 31, og = tid >> 5;     // 8 og x 16 outs = 128
  {
    float acc[16];
    #pragma unroll
    for (int r = 0; r < 16; ++r) acc[r] = 0.f;
    const float* in = s1 + tok * 129;
    const float* wp = WFP + og * 16;
    #pragma unroll 2
    for (int i = 0; i < 128; ++i) {
      float xv = in[i];
      #pragma unroll
      for (int q = 0; q < 4; ++q) {
        float4 w = *(const float4*)(wp + i * 128 + q * 4);
        acc[q*4+0] = fmaf(xv, w.x, acc[q*4+0]); acc[q*4+1] = fmaf(xv, w.y, acc[q*4+1]);
        acc[q*4+2] = fmaf(xv, w.z, acc[q*4+2]); acc[q*4+3] = fmaf(xv, w.w, acc[q*4+3]);
      }
    }
    #pragma unroll
    for (int r = 0; r < 16; ++r) acc[r] += ldin(b_fp, og * 16 + r, f);
    float* so = s2 + tok * 129 + og * 16;
    #pragma unroll
    for (int r = 0; r < 16; ++r) so[r] = acc[r];
    if (half == 0) {
      unsigned pk[8];
      #pragma unroll
      for (int q = 0; q < 8; ++q) pk[q] = pack2(acc[q*2], acc[q*2+1]);
      uint4* du = (uint4*)(u_out + (tok0 + tok) * 128 + og * 16);
      du[0] = make_uint4(pk[0],pk[1],pk[2],pk[3]); du[1] = make_uint4(pk[4],pk[5],pk[6],pk[7]);
    }
  }
  __syncthreads();
  // phase 2: 256 outputs of this half; og covers 32 outs
  float acc[32];
  #pragma unroll
  for (int r = 0; r < 32; ++r) acc[r] = 0.f;
  const float* in = s2 + tok * 129;
  const float* wp = WPR + half * 256 + og * 32;
  for (int i = 0; i < 128; ++i) {
    float xv = in[i];
    #pragma unroll
    for (int q = 0; q < 8; ++q) {
      float4 w = *(const float4*)(wp + i * 512 + q * 4);
      acc[q*4+0] = fmaf(xv, w.x, acc[q*4+0]); acc[q*4+1] = fmaf(xv, w.y, acc[q*4+1]);
      acc[q*4+2] = fmaf(xv, w.z, acc[q*4+2]); acc[q*4+3] = fmaf(xv, w.w, acc[q*4+3]);
    }
  }
  unsigned pk[16];
  if (half == 0) {
    #pragma unroll
    for (int q = 0; q < 16; ++q) pk[q] = pack2(acc[q*2], acc[q*2+1]);
    uint4* dd = (uint4*)(xpre + (tok0 + tok) * 256 + og * 32);
    #pragma unroll
    for (int q = 0; q < 4; ++q) dd[q] = make_uint4(pk[q*4],pk[q*4+1],pk[q*4+2],pk[q*4+3]);
  } else {
    #pragma unroll
    for (int q = 0; q < 16; ++q) pk[q] = pack2(silu(acc[q*2]), silu(acc[q*2+1]));
    uint4* dd = (uint4*)(siluz + (tok0 + tok) * 256 + og * 32);
    #pragma unroll
    for (int q = 0; q < 4; ++q) dd[q] = make_uint4(pk[q*4],pk[q*4+1],pk[q*4+2],pk[q*4+3]);
  }
}

// ---------------- convproj: depthwise conv + silu -> xc ; x_proj -> xdbl ----------------
__global__ __launch_bounds__(256) void convproj_k(
    const bf16* __restrict__ xpre, const void* __restrict__ cw, const void* __restrict__ cb,
    const float* __restrict__ WX, bf16* __restrict__ xc, float* __restrict__ xdbl,
    const int* __restrict__ flagp)
{
  __shared__ float xs[19 * 257];
  __shared__ float cs[16 * 257];
  const int f = *flagp;
  const int tid = threadIdx.x;
  const int tok0 = blockIdx.x * 16;
  for (int e = tid; e < 19 * 256; e += 256) {
    int tt = e >> 8, i = e & 255;
    int gtok = tok0 + tt - 3;
    xs[tt * 257 + i] = (gtok >= 0) ? b2f(xpre[gtok * 256 + i]) : 0.f;
  }
  __syncthreads();
  for (int e = tid; e < 16 * 256; e += 256) {
    int t = e >> 8, i = e & 255;
    int l = (tok0 + t) & (SEQ - 1);
    float acc = ldin(cb, i, f);
    #pragma unroll
    for (int k = 0; k < 4; ++k) {
      int off = k - 3;
      if (l + off >= 0) acc += xs[(t + 3 + off) * 257 + i] * ldin(cw, i * 4 + k, f);
    }
    float v = silu(acc);
    cs[t * 257 + i] = v;
    xc[(tok0 + t) * 256 + i] = f2b(v);
  }
  __syncthreads();
  const int tok = tid & 15, og = tid >> 4;   // 16 og x 4 outs (o<40 real)
  if (og < 10) {
    float acc[4] = {0.f, 0.f, 0.f, 0.f};
    const float* in = cs + tok * 257;
    const float* wp = WX + og * 4;
    for (int i = 0; i < 256; ++i) {
      float xv = in[i];
      float4 w = *(const float4*)(wp + i * 40);
      acc[0] = fmaf(xv, w.x, acc[0]); acc[1] = fmaf(xv, w.y, acc[1]);
      acc[2] = fmaf(xv, w.z, acc[2]); acc[3] = fmaf(xv, w.w, acc[3]);
    }
    *(float4*)(xdbl + (tok0 + tok) * 40 + og * 4) = make_float4(acc[0], acc[1], acc[2], acc[3]);
  }
}

// ---------------- chunked selective scan, 64-token chunks ----------------
// grid (64, 64): x = b*16+dg, y = chunk. block 256 = 16 dl x 16 s.
template<bool IS_C>
__global__ __launch_bounds__(256) void scan_k(
    const float* __restrict__ xdbl, const bf16* __restrict__ xc, const bf16* __restrict__ siluz,
    const void* __restrict__ A_log, const void* __restrict__ D_par, const void* __restrict__ dt_b,
    const float* __restrict__ WDT, float* __restrict__ summ, const float* __restrict__ hinit,
    bf16* __restrict__ g, const int* __restrict__ flagp)
{
  const int f = *flagp;
  const int tid = threadIdx.x;
  const int bb = blockIdx.x >> 4, dg = blockIdx.x & 15, c = blockIdx.y;
  const int dl = tid >> 4, s = tid & 15;
  const int j = s;
  const int d_loop = dg * 16 + dl;
  const int d_stg  = dg * 16 + j;
  const int tok_base = bb * SEQ + c * NCH;

  __shared__ float dt_l[NCH * 8];                    // 2 KB
  __shared__ float dx_l[NCH * 16 * 2];               // 8 KB (delta,xc pairs)
  __shared__ float bc_l[IS_C ? NCH * 16 * 2 : NCH * 16];
  __shared__ float g_l[IS_C ? NCH * 16 : 1];

  const float Aval = -__expf(ldin(A_log, d_loop * 16 + s, f));
  const float Dp = ldin(D_par, d_loop, f);
  const float dtb_j = ldin(dt_b, d_stg, f);
  float wdt[8];
  #pragma unroll
  for (int r = 0; r < 8; ++r) wdt[r] = WDT[r * 256 + d_stg];

  const int sidx = (blockIdx.x * NCHUNK + c) * 256 + tid;
  float h = IS_C ? hinit[sidx] : 0.f;
  float sdlt = 0.f;

  // stage dt + B(,C)
  for (int e2 = tid; e2 < NCH * 8; e2 += 256)
    dt_l[e2] = xdbl[(tok_base + (e2 >> 3)) * 40 + (e2 & 7)];
  #pragma unroll
  for (int k = 0; k < 4; ++k) {
    int e = tid + k * 256;               // e = t*16 + j
    int t = e >> 4;
    int tok = tok_base + t;
    float B = xdbl[tok * 40 + 8 + j];
    if (IS_C) {
      bc_l[e * 2 + 0] = B;
      bc_l[e * 2 + 1] = xdbl[tok * 40 + 24 + j];
    } else bc_l[e] = B;
  }
  __syncthreads();
  // delta = softplus(dt @ wdt + b) and xc -> paired LDS
  #pragma unroll
  for (int k = 0; k < 4; ++k) {
    int e = tid + k * 256;
    int t = e >> 4;
    float a = dtb_j;
    #pragma unroll
    for (int r = 0; r < 8; ++r) a = fmaf(dt_l[t * 8 + r], wdt[r], a);
    float xcv = b2f(xc[(tok_base + t) * 256 + d_stg]);
    *(float2*)(dx_l + e * 2) = make_float2(softplus(a), xcv);
  }
  __syncthreads();

  #pragma unroll 4
  for (int t = 0; t < NCH; ++t) {
    float2 dx = *(const float2*)(dx_l + (t * 16 + dl) * 2);
    float dlt = dx.x, xcv = dx.y;
    float dA = __expf(dlt * Aval);
    float du = dlt * xcv;
    if (!IS_C) sdlt += dlt;
    float B = IS_C ? bc_l[(t * 16 + s) * 2] : bc_l[t * 16 + s];
    h = fmaf(dA, h, du * B);
    if (IS_C) {
      float p = h * bc_l[(t * 16 + s) * 2 + 1];
      p = dpp_add<0x121>(p);   // row_ror:1
      p = dpp_add<0x122>(p);   // row_ror:2
      p = dpp_add<0x124>(p);   // row_ror:4
      p = dpp_add<0x128>(p);   // row_ror:8 -> all 16 lanes = sum_s
      if (s == 0) g_l[t * 16 + dl] = p + xcv * Dp;
    }
  }
  if (IS_C) {
    __syncthreads();
    #pragma unroll
    for (int k = 0; k < 4; ++k) {
      int e = tid + k * 256;
      int t = e >> 4;
      int tok = tok_base + t;
      g[tok * 256 + d_stg] = f2b(g_l[e] * b2f(siluz[tok * 256 + d_stg]));
    }
  } else {
    *(float2*)(summ + sidx * 2) = make_float2(__expf(Aval * sdlt), h);
  }
}

// phase B: exclusive scan over NCHUNK chunk summaries per (b,d,s)
__global__ __launch_bounds__(256) void scanB_k(const float* __restrict__ summ, float* __restrict__ hinit) {
  int bx = blockIdx.x, q = threadIdx.x;   // 64 blocks x 256
  float h = 0.f;
  for (int c = 0; c < NCHUNK; ++c) {
    int idx = (bx * NCHUNK + c) * 256 + q;
    hinit[idx] = h;
    float2 sv = *(const float2*)(summ + idx * 2);
    h = fmaf(sv.x, h, sv.y);
  }
}

// ---------------- back: m = W_mo@g ; rms2+u ; x wsw ; W_op + b + resid -> out ----------------
__global__ __launch_bounds__(256) void back_k(
    const bf16* __restrict__ g, const float* __restrict__ WMO, const void* __restrict__ w2,
    const bf16* __restrict__ u, const bf16* __restrict__ wsw, const float* __restrict__ WOP,
    const void* __restrict__ b_op, const void* __restrict__ x, void* __restrict__ out,
    const int* __restrict__ flagp)
{
  __shared__ float gs[16 * 257];
  __shared__ float ms[16 * 129];
  const int f = *flagp;
  const int tid = threadIdx.x;
  const int tok0 = blockIdx.x * 16;
  for (int e = tid; e < 16 * 256; e += 256) {
    int t = e >> 8, i = e & 255;
    gs[t * 257 + i] = b2f(g[(tok0 + t) * 256 + i]);
  }
  __syncthreads();
  {
    const int tok = tid & 15, og = tid >> 4;   // 16 og x 8 outs
    float acc[8];
    #pragma unroll
    for (int r = 0; r < 8; ++r) acc[r] = 0.f;
    const float* in = gs + tok * 257;
    const float* wp = WMO + og * 8;
    #pragma unroll 2
    for (int i = 0; i < 256; ++i) {
      float xv = in[i];
      #pragma unroll
      for (int q = 0; q < 2; ++q) {
        float4 w = *(const float4*)(wp + i * 128 + q * 4);
        acc[q*4+0] = fmaf(xv, w.x, acc[q*4+0]); acc[q*4+1] = fmaf(xv, w.y, acc[q*4+1]);
        acc[q*4+2] = fmaf(xv, w.z, acc[q*4+2]); acc[q*4+3] = fmaf(xv, w.w, acc[q*4+3]);
      }
    }
    float* so = ms + tok * 129 + og * 8;
    #pragma unroll
    for (int r = 0; r < 8; ++r) so[r] = acc[r];
  }
  __syncthreads();
  {  // rms2 + u, then gate by wsw; tid = tok*16 + r
    const int tok = tid >> 4, r = tid & 15;
    float ss = 0.f;
    #pragma unroll
    for (int k = 0; k < 8; ++k) { float v = ms[tok * 129 + r * 8 + k]; ss += v * v; }
    ss += __shfl_xor(ss, 1, 16); ss += __shfl_xor(ss, 2, 16);
    ss += __shfl_xor(ss, 4, 16); ss += __shfl_xor(ss, 8, 16);
    float sc = rsqrtf(ss * (1.f / 128.f) + EPS);
    #pragma unroll
    for (int k = 0; k < 8; ++k) {
      int i = r * 8 + k;
      int ga = (tok0 + tok) * 128 + i;
      float v = ms[tok * 129 + i] * sc * ldin(w2, i, f) + b2f(u[ga]);
      ms[tok * 129 + i] = v * b2f(wsw[ga]);
    }
  }
  __syncthreads();
  {
    const int tok = tid & 15, og = tid >> 4;   // 16 og x 4 outs
    float acc[4] = {0.f, 0.f, 0.f, 0.f};
    const float* in = ms + tok * 129;
    const float* wp = WOP + og * 4;
    #pragma unroll 2
    for (int i = 0; i < 128; ++i) {
      float xv = in[i];
      float4 w = *(const float4*)(wp + i * 64);
      acc[0] = fmaf(xv, w.x, acc[0]); acc[1] = fmaf(xv, w.y, acc[1]);
      acc[2] = fmaf(xv, w.z, acc[2]); acc[3] = fmaf(xv, w.w, acc[3]);
    }
    #pragma unroll
    for (int r = 0; r < 4; ++r) {
      int o = og * 4 + r;
      int ga = (tok0 + tok) * 64 + o;
      float v = acc[r] + ldin(b_op, o, f) + ldin(x, ga, f);
      if (f) ((float*)out)[ga] = v;
      else   ((bf16*)out)[ga] = f2b(v);
    }
  }
}

// ---------------- launch ----------------
extern "C" void kernel_launch(void* const* d_in, const int* in_sizes, int n_in,
                              void* d_out, int out_size, void* d_ws, size_t ws_size,
                              hipStream_t stream) {
  (void)in_sizes; (void)n_in; (void)out_size; (void)ws_size;
  const void* x        = d_in[0];
  const void* w_norm1  = d_in[1];
  const void* w_norm2  = d_in[2];
  const void* W_ip     = d_in[3];
  const void* b_ip     = d_in[4];
  const void* W_fp     = d_in[5];
  const void* b_fp     = d_in[6];
  const void* W_wp     = d_in[7];
  const void* b_wp     = d_in[8];
  const void* W_op     = d_in[9];
  const void* b_op     = d_in[10];
  const void* in_proj  = d_in[11];
  const void* conv_w   = d_in[12];
  const void* conv_b   = d_in[13];
  const void* x_proj   = d_in[14];
  const void* dt_projw = d_in[15];
  const void* dt_projb = d_in[16];
  const void* A_log    = d_in[17];
  const void* D_par    = d_in[18];
  const void* mo_w     = d_in[19];

  float* wsf   = (float*)d_ws;
  float* xdbl  = wsf + OFF_XDBL;
  bf16*  u_b   = (bf16*)(wsf + OFF_U);
  bf16*  wsw_b = (bf16*)(wsf + OFF_WSW);
  bf16*  siluz_b = (bf16*)(wsf + OFF_SILUZ);
  bf16*  xc_b  = (bf16*)(wsf + OFF_XC);
  bf16*  g_b   = (bf16*)(wsf + OFF_G);
  bf16*  t1_b  = (bf16*)(wsf + OFF_R1);
  float* hin   = wsf + OFF_R1;            // alias: t1 dead before scanB
  bf16*  xpre_b= (bf16*)(wsf + OFF_R2);
  float* summ  = wsf + OFF_R2;            // alias: xpre dead before scanA
  int*   flagp = (int*)(wsf + OFF_FLAG);

  detect_k<<<dim3(1), dim3(256), 0, stream>>>(x, flagp);
  transpose_all_k<<<dim3(592), dim3(256), 0, stream>>>(W_ip, W_fp, W_wp, in_proj, x_proj,
                                                       dt_projw, mo_w, W_op, wsf, flagp);
  front_k<<<dim3(NTOK / 32), dim3(256), 0, stream>>>(x, w_norm1, wsf + OFF_WIP, wsf + OFF_WWP,
                                                     b_ip, b_wp, t1_b, wsw_b, flagp);
  mid_k<<<dim3(NTOK / 32, 2), dim3(256), 0, stream>>>(t1_b, wsf + OFF_WFP, b_fp, wsf + OFF_WPR,
                                                      u_b, xpre_b, siluz_b, flagp);
  convproj_k<<<dim3(NTOK / 16), dim3(256), 0, stream>>>(xpre_b, conv_w, conv_b, wsf + OFF_WX,
                                                        xc_b, xdbl, flagp);
  scan_k<false><<<dim3(64, NCHUNK), dim3(256), 0, stream>>>(xdbl, xc_b, siluz_b, A_log, D_par,
                                                            dt_projb, wsf + OFF_WDT, summ, hin, g_b, flagp);
  scanB_k<<<dim3(64), dim3(256), 0, stream>>>(summ, hin);
  scan_k<true><<<dim3(64, NCHUNK), dim3(256), 0, stream>>>(xdbl, xc_b, siluz_b, A_log, D_par,
                                                           dt_projb, wsf + OFF_WDT, summ, hin, g_b, flagp);
  back_k<<<dim3(NTOK / 16), dim3(256), 0, stream>>>(g_b, wsf + OFF_WMO, w_norm2, u_b, wsw_b,
                                                    wsf + OFF_WOP, b_op, x, d_out, flagp);
}

// Round 5
// 257.733 us; speedup vs baseline: 2.2572x; 2.0477x over previous
//
#include <hip/hip_runtime.h>
#include <hip/hip_bf16.h>

typedef __hip_bfloat16 bf16;
typedef __attribute__((ext_vector_type(8))) short bf16x8;
typedef __attribute__((ext_vector_type(4))) float f32x4;
#define DEV __device__ __forceinline__

constexpr int SEQ  = 4096;
constexpr int NB   = 4;
constexpr int NTOK = NB * SEQ;          // 16384 tokens
constexpr float EPS = 1e-5f;
constexpr int NCH = 64;                 // scan chunk length
constexpr int NCHUNK = SEQ / NCH;       // 64 chunks/seq

// ---------------- workspace layout (float offsets) — 51.2 MB ----------------
// bf16 region sizing rule: elem_count/2 floats (R4 bug was /4 on three regions).
constexpr int OFF_WDT  = 0;                    // f32 [8][256] dt_proj^T
constexpr int OFF_WB   = 2048;                 // bf16 weight area (151552 shorts)
constexpr int WB_IP = 0;                       // [128][64]
constexpr int WB_WP = 8192;                    // [128][64]
constexpr int WB_FP = 16384;                   // [128][128]
constexpr int WB_PR = 32768;                   // [512][128]
constexpr int WB_MO = 98304;                   // [128][256]
constexpr int WB_OP = 131072;                  // [64][128]
constexpr int WB_XP = 139264;                  // [48][256] (40 real + 8 zero rows)
constexpr int WB_TOT = 151552;
constexpr int OFF_XDBL = OFF_WB + WB_TOT / 2;        // f32 [NTOK][40] (655360 f)
constexpr int OFF_XN   = OFF_XDBL + NTOK * 40;       // bf16 NTOK*64   -> 524288 f
constexpr int OFF_R1   = OFF_XN   + 524288;          // t1 / hinit / m_b (1048576 f)
constexpr int OFF_WSW  = OFF_R1   + 1048576;         // bf16 NTOK*128  -> 1048576 f
constexpr int OFF_U    = OFF_WSW  + 1048576;         // bf16 NTOK*128  -> 1048576 f
constexpr int OFF_R2   = OFF_U    + 1048576;         // xpre / summ    (2097152 f)
constexpr int OFF_SILUZ= OFF_R2   + 2097152;         // bf16 NTOK*256  -> 2097152 f
constexpr int OFF_XC   = OFF_SILUZ+ 2097152;         // bf16 NTOK*256
constexpr int OFF_G    = OFF_XC   + 2097152;         // bf16 NTOK*256
constexpr int OFF_FLAG = OFF_G    + 2097152;         // int dtype flag

DEV float b2f(bf16 x) { return __bfloat162float(x); }
DEV bf16 f2b(float x) { return __float2bfloat16(x); }
DEV float ldin(const void* p, int i, int f) {
  return f ? ((const float*)p)[i] : b2f(((const bf16*)p)[i]);
}
template<int CTRL>
DEV float dpp_add(float v) {
  int r = __builtin_amdgcn_update_dpp(0, __float_as_int(v), CTRL, 0xF, 0xF, false);
  return v + __int_as_float(r);
}
DEV float softplus(float a) { return (a > 20.f) ? a : log1pf(__expf(a)); }
DEV float silu(float a) { return a / (1.f + __expf(-a)); }

// ---------------- dtype detector ----------------
__global__ void detect_k(const void* __restrict__ x, int* __restrict__ flagp) {
  __shared__ int cnt;
  if (threadIdx.x == 0) cnt = 0;
  __syncthreads();
  float v = b2f(((const bf16*)x)[threadIdx.x]);
  int ok = (v == v) && fabsf(v) > 1e-4f && fabsf(v) < 100.f;
  atomicAdd(&cnt, ok);
  __syncthreads();
  if (threadIdx.x == 0) *flagp = (cnt > 204) ? 0 : 1;
}

// ---------------- weight prep: bf16 copies (native [N][K] layout) + WDT f32 ----------------
DEV void cpw(int e, int base, int count, const void* __restrict__ src,
             bf16* __restrict__ wb, int f) {
  int r = e - base;
  if (r >= 0 && r < count) wb[base + r] = f2b(ldin(src, r, f));
}
__global__ __launch_bounds__(256) void prep_k(
    const void* __restrict__ w_ip, const void* __restrict__ w_wp, const void* __restrict__ w_fp,
    const void* __restrict__ w_pr, const void* __restrict__ w_mo, const void* __restrict__ w_op,
    const void* __restrict__ w_x,  const void* __restrict__ w_dt,
    float* __restrict__ wsf, const int* __restrict__ flagp)
{
  int f = *flagp;
  int e = blockIdx.x * 256 + threadIdx.x;   // 592*256 covers 151552
  bf16* wb = (bf16*)(wsf + OFF_WB);
  cpw(e, WB_IP, 8192,  w_ip, wb, f);
  cpw(e, WB_WP, 8192,  w_wp, wb, f);
  cpw(e, WB_FP, 16384, w_fp, wb, f);
  cpw(e, WB_PR, 65536, w_pr, wb, f);
  cpw(e, WB_MO, 32768, w_mo, wb, f);
  cpw(e, WB_OP, 8192,  w_op, wb, f);
  {  // x_proj padded to 48 rows
    int r = e - WB_XP;
    if (r >= 0 && r < 12288) wb[WB_XP + r] = (r < 10240) ? f2b(ldin(w_x, r, f)) : f2b(0.f);
  }
  if (e < 2048) {  // WDT[r][d] = dt_proj[d][r]
    int r = e >> 8, d = e & 255;
    wsf[OFF_WDT + e] = ldin(w_dt, d * 8 + r, f);
  }
}

// ---------------- rms1: x -> xn (bf16) ----------------
__global__ __launch_bounds__(256) void rms1_k(const void* __restrict__ x, const void* __restrict__ w,
                                              bf16* __restrict__ xn, const int* __restrict__ flagp) {
  int f = *flagp;
  int lane = threadIdx.x & 63;
  int token = blockIdx.x * 4 + (threadIdx.x >> 6);
  float v = ldin(x, token * 64 + lane, f);
  float ss = v * v;
  #pragma unroll
  for (int m = 32; m >= 1; m >>= 1) ss += __shfl_xor(ss, m, 64);
  float sc = rsqrtf(ss * (1.f / 64.f) + EPS);
  xn[token * 64 + lane] = f2b(v * sc * ldin(w, lane, f));
}

// ---------------- generic wave GEMM: 16 tokens x (NT*16) outs, K contraction ----------------
// A [.][K] row-major bf16 (global), W [N][K] row-major bf16 (global).
// A-frag: A[m=lane&15][k=quad*8+j]; B-frag: W[n=lane&15][k=quad*8+j]; D: col=lane&15(n), row=quad*4+r(m)
template<int K, int NT>
DEV void wave_gemm(const bf16* __restrict__ A, int a_stride, int tok0,
                   const bf16* __restrict__ W, int n0, f32x4* acc)
{
  const int lane = threadIdx.x & 63;
  const int m = lane & 15, quad = lane >> 4;
  const bf16* ap = A + (tok0 + m) * a_stride + quad * 8;
  #pragma unroll
  for (int k0 = 0; k0 < K; k0 += 32) {
    bf16x8 af = *(const bf16x8*)(ap + k0);
    #pragma unroll
    for (int nt = 0; nt < NT; ++nt) {
      const bf16* bp = W + (n0 + nt * 16 + m) * K + k0 + quad * 8;
      bf16x8 bfr = *(const bf16x8*)bp;
      acc[nt] = __builtin_amdgcn_mfma_f32_16x16x32_bf16(af, bfr, acc[nt], 0, 0, 0);
    }
  }
}

// ---------------- front: t1 = xn@Wip^T + b_ip ; wsw = silu(xn@Wwp^T + b_wp) ----------------
__global__ __launch_bounds__(256) void front_mm_k(
    const bf16* __restrict__ xn, const float* __restrict__ wsf,
    const void* __restrict__ b_ip, const void* __restrict__ b_wp,
    bf16* __restrict__ t1, bf16* __restrict__ wsw, const int* __restrict__ flagp)
{
  const int f = *flagp;
  const bf16* wb = (const bf16*)(wsf + OFF_WB);
  const int w = threadIdx.x >> 6;
  const int tok0 = blockIdx.x * 64 + w * 16;
  const int y = blockIdx.y;                 // 0,1: t1 ; 2,3: wsw
  const bool isW = y >= 2;
  const int n0 = (y & 1) * 64;
  const bf16* W = wb + (isW ? WB_WP : WB_IP);
  const void* bia = isW ? b_wp : b_ip;
  bf16* out = isW ? wsw : t1;
  f32x4 acc[4] = {{0,0,0,0},{0,0,0,0},{0,0,0,0},{0,0,0,0}};
  wave_gemm<64, 4>(xn, 64, tok0, W, n0, acc);
  const int lane = threadIdx.x & 63, m = lane & 15, quad = lane >> 4;
  #pragma unroll
  for (int nt = 0; nt < 4; ++nt) {
    int n = n0 + nt * 16 + m;
    float bv = ldin(bia, n, f);
    #pragma unroll
    for (int r = 0; r < 4; ++r) {
      float v = acc[nt][r] + bv;
      if (isW) v = silu(v);
      out[(tok0 + quad * 4 + r) * 128 + n] = f2b(v);
    }
  }
}

// ---------------- midA: u = t1@Wfp^T + b_fp ----------------
__global__ __launch_bounds__(256) void midA_k(
    const bf16* __restrict__ t1, const float* __restrict__ wsf, const void* __restrict__ b_fp,
    bf16* __restrict__ u, const int* __restrict__ flagp)
{
  const int f = *flagp;
  const bf16* W = (const bf16*)(wsf + OFF_WB) + WB_FP;
  const int w = threadIdx.x >> 6;
  const int tok0 = blockIdx.x * 64 + w * 16;
  const int n0 = blockIdx.y * 64;
  f32x4 acc[4] = {{0,0,0,0},{0,0,0,0},{0,0,0,0},{0,0,0,0}};
  wave_gemm<128, 4>(t1, 128, tok0, W, n0, acc);
  const int lane = threadIdx.x & 63, m = lane & 15, quad = lane >> 4;
  #pragma unroll
  for (int nt = 0; nt < 4; ++nt) {
    int n = n0 + nt * 16 + m;
    float bv = ldin(b_fp, n, f);
    #pragma unroll
    for (int r = 0; r < 4; ++r)
      u[(tok0 + quad * 4 + r) * 128 + n] = f2b(acc[nt][r] + bv);
  }
}

// ---------------- midB: xz = u@in_proj^T ; n<256 -> xpre, else silu -> siluz ----------------
__global__ __launch_bounds__(256) void midB_k(
    const bf16* __restrict__ u, const float* __restrict__ wsf,
    bf16* __restrict__ xpre, bf16* __restrict__ siluz)
{
  const bf16* W = (const bf16*)(wsf + OFF_WB) + WB_PR;
  const int w = threadIdx.x >> 6;
  const int tok0 = blockIdx.x * 64 + w * 16;
  const int n0 = blockIdx.y * 64;           // 0..448
  f32x4 acc[4] = {{0,0,0,0},{0,0,0,0},{0,0,0,0},{0,0,0,0}};
  wave_gemm<128, 4>(u, 128, tok0, W, n0, acc);
  const int lane = threadIdx.x & 63, m = lane & 15, quad = lane >> 4;
  #pragma unroll
  for (int nt = 0; nt < 4; ++nt) {
    int n = n0 + nt * 16 + m;
    #pragma unroll
    for (int r = 0; r < 4; ++r) {
      int tok = tok0 + quad * 4 + r;
      float v = acc[nt][r];
      if (n < 256) xpre[tok * 256 + n] = f2b(v);
      else         siluz[tok * 256 + (n - 256)] = f2b(silu(v));
    }
  }
}

// ---------------- conv (depthwise w4 + silu) + x_proj MFMA -> xc, xdbl ----------------
__global__ __launch_bounds__(256) void conv_k(
    const bf16* __restrict__ xpre, const void* __restrict__ cw, const void* __restrict__ cb,
    const float* __restrict__ wsf, bf16* __restrict__ xc, float* __restrict__ xdbl,
    const int* __restrict__ flagp)
{
  __shared__ short xh[35 * 256];
  __shared__ short cs[32 * 264];
  const int f = *flagp;
  const int tid = threadIdx.x;
  const int tok0 = blockIdx.x * 32;
  for (int c = tid; c < 1120; c += 256) {
    int e0 = c * 8;
    int tt = e0 >> 8, i = e0 & 255;
    int gtok = tok0 + tt - 3;
    uint4* dst = (uint4*)(xh + e0);
    if (gtok >= 0) *dst = *(const uint4*)(xpre + gtok * 256 + i);
    else           *dst = make_uint4(0, 0, 0, 0);
  }
  __syncthreads();
  {  // conv: thread = channel, loop tokens
    const int ch = tid;
    float cwv[4];
    #pragma unroll
    for (int k = 0; k < 4; ++k) cwv[k] = ldin(cw, ch * 4 + k, f);
    const float cbv = ldin(cb, ch, f);
    for (int t = 0; t < 32; ++t) {
      int l = (tok0 + t) & (SEQ - 1);
      float acc = cbv;
      #pragma unroll
      for (int k = 0; k < 4; ++k)
        if (l + k - 3 >= 0) acc += b2f(((const bf16*)xh)[(t + k) * 256 + ch]) * cwv[k];
      bf16 v = f2b(silu(acc));
      ((bf16*)cs)[t * 264 + ch] = v;
      xc[(tok0 + t) * 256 + ch] = v;
    }
  }
  __syncthreads();
  const int w = tid >> 6;
  if (w < 2) {
    const bf16* Wx = (const bf16*)(wsf + OFF_WB) + WB_XP;
    const int lane = tid & 63, m = lane & 15, quad = lane >> 4;
    f32x4 acc[3] = {{0,0,0,0},{0,0,0,0},{0,0,0,0}};
    #pragma unroll
    for (int k0 = 0; k0 < 256; k0 += 32) {
      bf16x8 af = *(const bf16x8*)&cs[(w * 16 + m) * 264 + k0 + quad * 8];
      #pragma unroll
      for (int nt = 0; nt < 3; ++nt) {
        bf16x8 bfr = *(const bf16x8*)(Wx + (nt * 16 + m) * 256 + k0 + quad * 8);
        acc[nt] = __builtin_amdgcn_mfma_f32_16x16x32_bf16(af, bfr, acc[nt], 0, 0, 0);
      }
    }
    #pragma unroll
    for (int nt = 0; nt < 3; ++nt) {
      int n = nt * 16 + m;
      if (n < 40) {
        #pragma unroll
        for (int r = 0; r < 4; ++r)
          xdbl[(tok0 + w * 16 + quad * 4 + r) * 40 + n] = acc[nt][r];
      }
    }
  }
}

// ---------------- chunked selective scan (unchanged — R3-verified) ----------------
template<bool IS_C>
__global__ __launch_bounds__(256) void scan_k(
    const float* __restrict__ xdbl, const bf16* __restrict__ xc, const bf16* __restrict__ siluz,
    const void* __restrict__ A_log, const void* __restrict__ D_par, const void* __restrict__ dt_b,
    const float* __restrict__ WDT, float* __restrict__ summ, const float* __restrict__ hinit,
    bf16* __restrict__ g, const int* __restrict__ flagp)
{
  const int f = *flagp;
  const int tid = threadIdx.x;
  const int bb = blockIdx.x >> 4, dg = blockIdx.x & 15, c = blockIdx.y;
  const int dl = tid >> 4, s = tid & 15;
  const int j = s;
  const int d_loop = dg * 16 + dl;
  const int d_stg  = dg * 16 + j;
  const int tok_base = bb * SEQ + c * NCH;

  __shared__ float dt_l[NCH * 8];
  __shared__ float dx_l[NCH * 16 * 2];
  __shared__ float bc_l[IS_C ? NCH * 16 * 2 : NCH * 16];
  __shared__ float g_l[IS_C ? NCH * 16 : 1];

  const float Aval = -__expf(ldin(A_log, d_loop * 16 + s, f));
  const float Dp = ldin(D_par, d_loop, f);
  const float dtb_j = ldin(dt_b, d_stg, f);
  float wdt[8];
  #pragma unroll
  for (int r = 0; r < 8; ++r) wdt[r] = WDT[r * 256 + d_stg];

  const int sidx = (blockIdx.x * NCHUNK + c) * 256 + tid;
  float h = IS_C ? hinit[sidx] : 0.f;
  float sdlt = 0.f;

  for (int e2 = tid; e2 < NCH * 8; e2 += 256)
    dt_l[e2] = xdbl[(tok_base + (e2 >> 3)) * 40 + (e2 & 7)];
  #pragma unroll
  for (int k = 0; k < 4; ++k) {
    int e = tid + k * 256;
    int t = e >> 4;
    int tok = tok_base + t;
    float B = xdbl[tok * 40 + 8 + j];
    if (IS_C) {
      bc_l[e * 2 + 0] = B;
      bc_l[e * 2 + 1] = xdbl[tok * 40 + 24 + j];
    } else bc_l[e] = B;
  }
  __syncthreads();
  #pragma unroll
  for (int k = 0; k < 4; ++k) {
    int e = tid + k * 256;
    int t = e >> 4;
    float a = dtb_j;
    #pragma unroll
    for (int r = 0; r < 8; ++r) a = fmaf(dt_l[t * 8 + r], wdt[r], a);
    float xcv = b2f(xc[(tok_base + t) * 256 + d_stg]);
    *(float2*)(dx_l + e * 2) = make_float2(softplus(a), xcv);
  }
  __syncthreads();

  #pragma unroll 4
  for (int t = 0; t < NCH; ++t) {
    float2 dx = *(const float2*)(dx_l + (t * 16 + dl) * 2);
    float dlt = dx.x, xcv = dx.y;
    float dA = __expf(dlt * Aval);
    float du = dlt * xcv;
    if (!IS_C) sdlt += dlt;
    float B = IS_C ? bc_l[(t * 16 + s) * 2] : bc_l[t * 16 + s];
    h = fmaf(dA, h, du * B);
    if (IS_C) {
      float p = h * bc_l[(t * 16 + s) * 2 + 1];
      p = dpp_add<0x121>(p);
      p = dpp_add<0x122>(p);
      p = dpp_add<0x124>(p);
      p = dpp_add<0x128>(p);
      if (s == 0) g_l[t * 16 + dl] = p + xcv * Dp;
    }
  }
  if (IS_C) {
    __syncthreads();
    #pragma unroll
    for (int k = 0; k < 4; ++k) {
      int e = tid + k * 256;
      int t = e >> 4;
      int tok = tok_base + t;
      g[tok * 256 + d_stg] = f2b(g_l[e] * b2f(siluz[tok * 256 + d_stg]));
    }
  } else {
    *(float2*)(summ + sidx * 2) = make_float2(__expf(Aval * sdlt), h);
  }
}

__global__ __launch_bounds__(256) void scanB_k(const float* __restrict__ summ, float* __restrict__ hinit) {
  int bx = blockIdx.x, q = threadIdx.x;
  float h = 0.f;
  for (int c = 0; c < NCHUNK; ++c) {
    int idx = (bx * NCHUNK + c) * 256 + q;
    hinit[idx] = h;
    float2 sv = *(const float2*)(summ + idx * 2);
    h = fmaf(sv.x, h, sv.y);
  }
}

// ---------------- backA: m = g@Wmo^T ----------------
__global__ __launch_bounds__(256) void backA_k(
    const bf16* __restrict__ g, const float* __restrict__ wsf, bf16* __restrict__ m_b)
{
  const bf16* W = (const bf16*)(wsf + OFF_WB) + WB_MO;
  const int w = threadIdx.x >> 6;
  const int tok0 = blockIdx.x * 64 + w * 16;
  const int n0 = blockIdx.y * 64;
  f32x4 acc[4] = {{0,0,0,0},{0,0,0,0},{0,0,0,0},{0,0,0,0}};
  wave_gemm<256, 4>(g, 256, tok0, W, n0, acc);
  const int lane = threadIdx.x & 63, m = lane & 15, quad = lane >> 4;
  #pragma unroll
  for (int nt = 0; nt < 4; ++nt) {
    int n = n0 + nt * 16 + m;
    #pragma unroll
    for (int r = 0; r < 4; ++r)
      m_b[(tok0 + quad * 4 + r) * 128 + n] = f2b(acc[nt][r]);
  }
}

// ---------------- backB: rms2(m)*w2 + u, gate wsw, @Wop^T + b_op + resid -> out ----------------
__global__ __launch_bounds__(256) void backB_k(
    const bf16* __restrict__ m_b, const void* __restrict__ w2, const bf16* __restrict__ u,
    const bf16* __restrict__ wsw, const float* __restrict__ wsf, const void* __restrict__ b_op,
    const void* __restrict__ x, void* __restrict__ out, const int* __restrict__ flagp)
{
  __shared__ short ms[32 * 136];
  const int f = *flagp;
  const int tid = threadIdx.x;
  const int tok0 = blockIdx.x * 32;
  {
    const int t = tid >> 3, r = tid & 7;
    const int token = tok0 + t;
    float mv[16];
    float ss = 0.f;
    #pragma unroll
    for (int k = 0; k < 16; ++k) {
      mv[k] = b2f(m_b[token * 128 + r * 16 + k]);
      ss += mv[k] * mv[k];
    }
    ss += __shfl_xor(ss, 1, 8); ss += __shfl_xor(ss, 2, 8); ss += __shfl_xor(ss, 4, 8);
    float sc = rsqrtf(ss * (1.f / 128.f) + EPS);
    #pragma unroll
    for (int k = 0; k < 16; ++k) {
      int i = r * 16 + k;
      float v = mv[k] * sc * ldin(w2, i, f) + b2f(u[token * 128 + i]);
      ((bf16*)ms)[t * 136 + i] = f2b(v * b2f(wsw[token * 128 + i]));
    }
  }
  __syncthreads();
  const int w = tid >> 6;
  if (w < 2) {
    const bf16* Wo = (const bf16*)(wsf + OFF_WB) + WB_OP;
    const int lane = tid & 63, m = lane & 15, quad = lane >> 4;
    f32x4 acc[4] = {{0,0,0,0},{0,0,0,0},{0,0,0,0},{0,0,0,0}};
    #pragma unroll
    for (int k0 = 0; k0 < 128; k0 += 32) {
      bf16x8 af = *(const bf16x8*)&ms[(w * 16 + m) * 136 + k0 + quad * 8];
      #pragma unroll
      for (int nt = 0; nt < 4; ++nt) {
        bf16x8 bfr = *(const bf16x8*)(Wo + (nt * 16 + m) * 128 + k0 + quad * 8);
        acc[nt] = __builtin_amdgcn_mfma_f32_16x16x32_bf16(af, bfr, acc[nt], 0, 0, 0);
      }
    }
    #pragma unroll
    for (int nt = 0; nt < 4; ++nt) {
      int n = nt * 16 + m;
      float bv = ldin(b_op, n, f);
      #pragma unroll
      for (int r = 0; r < 4; ++r) {
        int token = tok0 + w * 16 + quad * 4 + r;
        float v = acc[nt][r] + bv + ldin(x, token * 64 + n, f);
        if (f) ((float*)out)[token * 64 + n] = v;
        else   ((bf16*)out)[token * 64 + n] = f2b(v);
      }
    }
  }
}

// ---------------- launch ----------------
extern "C" void kernel_launch(void* const* d_in, const int* in_sizes, int n_in,
                              void* d_out, int out_size, void* d_ws, size_t ws_size,
                              hipStream_t stream) {
  (void)in_sizes; (void)n_in; (void)out_size; (void)ws_size;
  const void* x        = d_in[0];
  const void* w_norm1  = d_in[1];
  const void* w_norm2  = d_in[2];
  const void* W_ip     = d_in[3];
  const void* b_ip     = d_in[4];
  const void* W_fp     = d_in[5];
  const void* b_fp     = d_in[6];
  const void* W_wp     = d_in[7];
  const void* b_wp     = d_in[8];
  const void* W_op     = d_in[9];
  const void* b_op     = d_in[10];
  const void* in_proj  = d_in[11];
  const void* conv_w   = d_in[12];
  const void* conv_b   = d_in[13];
  const void* x_proj   = d_in[14];
  const void* dt_projw = d_in[15];
  const void* dt_projb = d_in[16];
  const void* A_log    = d_in[17];
  const void* D_par    = d_in[18];
  const void* mo_w     = d_in[19];

  float* wsf    = (float*)d_ws;
  float* xdbl   = wsf + OFF_XDBL;
  bf16*  xn_b   = (bf16*)(wsf + OFF_XN);
  bf16*  t1_b   = (bf16*)(wsf + OFF_R1);
  float* hin    = wsf + OFF_R1;
  bf16*  mb_b   = (bf16*)(wsf + OFF_R1);
  bf16*  wsw_b  = (bf16*)(wsf + OFF_WSW);
  bf16*  u_b    = (bf16*)(wsf + OFF_U);
  bf16*  xpre_b = (bf16*)(wsf + OFF_R2);
  float* summ   = wsf + OFF_R2;
  bf16*  siluz_b= (bf16*)(wsf + OFF_SILUZ);
  bf16*  xc_b   = (bf16*)(wsf + OFF_XC);
  bf16*  g_b    = (bf16*)(wsf + OFF_G);
  int*   flagp  = (int*)(wsf + OFF_FLAG);

  detect_k<<<dim3(1), dim3(256), 0, stream>>>(x, flagp);
  prep_k<<<dim3(592), dim3(256), 0, stream>>>(W_ip, W_wp, W_fp, in_proj, mo_w, W_op,
                                              x_proj, dt_projw, wsf, flagp);
  rms1_k<<<dim3(NTOK / 4), dim3(256), 0, stream>>>(x, w_norm1, xn_b, flagp);
  front_mm_k<<<dim3(NTOK / 64, 4), dim3(256), 0, stream>>>(xn_b, wsf, b_ip, b_wp, t1_b, wsw_b, flagp);
  midA_k<<<dim3(NTOK / 64, 2), dim3(256), 0, stream>>>(t1_b, wsf, b_fp, u_b, flagp);
  midB_k<<<dim3(NTOK / 64, 8), dim3(256), 0, stream>>>(u_b, wsf, xpre_b, siluz_b);
  conv_k<<<dim3(NTOK / 32), dim3(256), 0, stream>>>(xpre_b, conv_w, conv_b, wsf, xc_b, xdbl, flagp);
  scan_k<false><<<dim3(64, NCHUNK), dim3(256), 0, stream>>>(xdbl, xc_b, siluz_b, A_log, D_par,
                                                            dt_projb, wsf + OFF_WDT, summ, hin, g_b, flagp);
  scanB_k<<<dim3(64), dim3(256), 0, stream>>>(summ, hin);
  scan_k<true><<<dim3(64, NCHUNK), dim3(256), 0, stream>>>(xdbl, xc_b, siluz_b, A_log, D_par,
                                                           dt_projb, wsf + OFF_WDT, summ, hin, g_b, flagp);
  backA_k<<<dim3(NTOK / 64, 2), dim3(256), 0, stream>>>(g_b, wsf, mb_b);
  backB_k<<<dim3(NTOK / 32), dim3(256), 0, stream>>>(mb_b, w_norm2, u_b, wsw_b, wsf, b_op, x, d_out, flagp);
}

// Round 6
// 241.942 us; speedup vs baseline: 2.4045x; 1.0653x over previous
//
#include <hip/hip_runtime.h>
#include <hip/hip_bf16.h>

typedef __hip_bfloat16 bf16;
typedef __attribute__((ext_vector_type(8))) short bf16x8;
typedef __attribute__((ext_vector_type(4))) float f32x4;
#define DEV __device__ __forceinline__

constexpr int SEQ  = 4096;
constexpr int NB   = 4;
constexpr int NTOK = NB * SEQ;          // 16384 tokens
constexpr float EPS = 1e-5f;
constexpr int NCH = 64;                 // scan chunk length
constexpr int NCHUNK = SEQ / NCH;       // 64 chunks/seq

// ---------------- workspace layout (float offsets) — 51.2 MB ----------------
constexpr int OFF_WDT  = 0;                    // f32 [8][256] dt_proj^T
constexpr int OFF_WB   = 2048;                 // bf16 weight area (151552 shorts)
constexpr int WB_IP = 0;                       // [128][64]
constexpr int WB_WP = 8192;                    // [128][64]
constexpr int WB_FP = 16384;                   // [128][128]
constexpr int WB_PR = 32768;                   // [512][128]
constexpr int WB_MO = 98304;                   // [128][256]
constexpr int WB_OP = 131072;                  // [64][128]
constexpr int WB_XP = 139264;                  // [48][256] (40 real + 8 zero rows)
constexpr int WB_TOT = 151552;
constexpr int OFF_XDBL = OFF_WB + WB_TOT / 2;        // f32 [NTOK][40] (655360 f)
constexpr int OFF_R1   = OFF_XDBL + NTOK * 40;       // t1 (bf16 NTOK*128) / hinit (1048576 f)
constexpr int OFF_WSW  = OFF_R1   + 1048576;         // bf16 NTOK*128  -> 1048576 f
constexpr int OFF_U    = OFF_WSW  + 1048576;         // bf16 NTOK*128  -> 1048576 f
constexpr int OFF_R2   = OFF_U    + 1048576;         // xpre / summ    (2097152 f)
constexpr int OFF_SILUZ= OFF_R2   + 2097152;         // bf16 NTOK*256  -> 2097152 f
constexpr int OFF_XC   = OFF_SILUZ+ 2097152;         // bf16 NTOK*256
constexpr int OFF_G    = OFF_XC   + 2097152;         // bf16 NTOK*256
constexpr int OFF_FLAG = OFF_G    + 2097152;         // int dtype flag

DEV float b2f(bf16 x) { return __bfloat162float(x); }
DEV bf16 f2b(float x) { return __float2bfloat16(x); }
DEV short shof(bf16 h) { short s; __builtin_memcpy(&s, &h, 2); return s; }
DEV float ldin(const void* p, int i, int f) {
  return f ? ((const float*)p)[i] : b2f(((const bf16*)p)[i]);
}
DEV unsigned pack2(float a, float b) {
  bf16 ha = f2b(a), hb = f2b(b);
  unsigned short ua, ub;
  __builtin_memcpy(&ua, &ha, 2); __builtin_memcpy(&ub, &hb, 2);
  return (unsigned)ua | ((unsigned)ub << 16);
}
template<int CTRL>
DEV float dpp_add(float v) {
  int r = __builtin_amdgcn_update_dpp(0, __float_as_int(v), CTRL, 0xF, 0xF, false);
  return v + __int_as_float(r);
}
DEV float softplus(float a) { return (a > 20.f) ? a : log1pf(__expf(a)); }
DEV float silu(float a) { return a / (1.f + __expf(-a)); }

// ---------------- prep: inline dtype detect + bf16 weight copies + WDT f32 ----------------
DEV void cpw(int e, int base, int count, const void* __restrict__ src,
             bf16* __restrict__ wb, int f) {
  int r = e - base;
  if (r >= 0 && r < count) wb[base + r] = f2b(ldin(src, r, f));
}
__global__ __launch_bounds__(256) void prep_k(
    const void* __restrict__ w_ip, const void* __restrict__ w_wp, const void* __restrict__ w_fp,
    const void* __restrict__ w_pr, const void* __restrict__ w_mo, const void* __restrict__ w_op,
    const void* __restrict__ w_x,  const void* __restrict__ w_dt,
    const void* __restrict__ x, float* __restrict__ wsf, int* __restrict__ flagp)
{
  __shared__ int cnt;
  if (threadIdx.x == 0) cnt = 0;
  __syncthreads();
  {
    float v = b2f(((const bf16*)x)[threadIdx.x]);
    int ok = (v == v) && fabsf(v) > 1e-4f && fabsf(v) < 100.f;
    atomicAdd(&cnt, ok);
  }
  __syncthreads();
  int f = (cnt > 204) ? 0 : 1;
  if (blockIdx.x == 0 && threadIdx.x == 0) *flagp = f;

  int e = blockIdx.x * 256 + threadIdx.x;   // 592*256 covers 151552
  bf16* wb = (bf16*)(wsf + OFF_WB);
  cpw(e, WB_IP, 8192,  w_ip, wb, f);
  cpw(e, WB_WP, 8192,  w_wp, wb, f);
  cpw(e, WB_FP, 16384, w_fp, wb, f);
  cpw(e, WB_PR, 65536, w_pr, wb, f);
  cpw(e, WB_MO, 32768, w_mo, wb, f);
  cpw(e, WB_OP, 8192,  w_op, wb, f);
  {
    int r = e - WB_XP;
    if (r >= 0 && r < 12288) wb[WB_XP + r] = (r < 10240) ? f2b(ldin(w_x, r, f)) : f2b(0.f);
  }
  if (e < 2048) {
    int r = e >> 8, d = e & 255;
    wsf[OFF_WDT + e] = ldin(w_dt, d * 8 + r, f);
  }
}

// ---------------- front: rms1 fused + t1 = xn@Wip^T+b ; wsw = silu(xn@Wwp^T+b) ----------------
// grid NTOK/32. Block = 32 tokens. Waves: mt=w&1 (16-token m-tile), wt=w>>1 (ip/wp).
__global__ __launch_bounds__(256) void front_k(
    const void* __restrict__ x, const void* __restrict__ w1, const float* __restrict__ wsf,
    const void* __restrict__ b_ip, const void* __restrict__ b_wp,
    bf16* __restrict__ t1, bf16* __restrict__ wsw, const int* __restrict__ flagp)
{
  __shared__ short xn[32 * 72];
  const int f = *flagp;
  const int tid = threadIdx.x;
  const int tok0 = blockIdx.x * 32;
  {  // rms: 8 threads per token, 8 channels each
    const int token = tid >> 3, r = tid & 7;
    float v[8]; float ss = 0.f;
    #pragma unroll
    for (int k = 0; k < 8; ++k) {
      v[k] = ldin(x, (tok0 + token) * 64 + r * 8 + k, f);
      ss += v[k] * v[k];
    }
    ss += __shfl_xor(ss, 1, 8); ss += __shfl_xor(ss, 2, 8); ss += __shfl_xor(ss, 4, 8);
    float sc = rsqrtf(ss * (1.f / 64.f) + EPS);
    unsigned* dst = (unsigned*)xn + token * 36 + r * 4;
    #pragma unroll
    for (int k = 0; k < 4; ++k) {
      int i = r * 8 + k * 2;
      dst[k] = pack2(v[k*2] * sc * ldin(w1, i, f), v[k*2+1] * sc * ldin(w1, i + 1, f));
    }
  }
  __syncthreads();
  const int lane = tid & 63, m = lane & 15, q = lane >> 4;
  const int w = tid >> 6, mt = w & 1, wt = w >> 1;
  const bf16* W = (const bf16*)(wsf + OFF_WB) + (wt ? WB_WP : WB_IP);
  const void* bia = wt ? b_wp : b_ip;
  bf16* out = wt ? wsw : t1;
  bf16x8 a0 = *(const bf16x8*)&xn[(mt * 16 + m) * 72 + q * 8];
  bf16x8 a1 = *(const bf16x8*)&xn[(mt * 16 + m) * 72 + 32 + q * 8];
  #pragma unroll
  for (int nt = 0; nt < 8; ++nt) {
    bf16x8 b0 = *(const bf16x8*)(W + (nt * 16 + m) * 64 + q * 8);
    bf16x8 b1 = *(const bf16x8*)(W + (nt * 16 + m) * 64 + 32 + q * 8);
    f32x4 acc = {0.f, 0.f, 0.f, 0.f};
    acc = __builtin_amdgcn_mfma_f32_16x16x32_bf16(a0, b0, acc, 0, 0, 0);
    acc = __builtin_amdgcn_mfma_f32_16x16x32_bf16(a1, b1, acc, 0, 0, 0);
    int n = nt * 16 + m;
    float bv = ldin(bia, n, f);
    #pragma unroll
    for (int r = 0; r < 4; ++r) {
      float v = acc[r] + bv;
      if (wt) v = silu(v);
      out[(tok0 + mt * 16 + q * 4 + r) * 128 + n] = f2b(v);
    }
  }
}

// ---------------- mid: u = t1@Wfp^T+b (LDS+global) ; xz = u@Wpr^T -> xpre/siluz ----------------
// grid NTOK/32. waves: mt=w&1, ng=w>>1.
__global__ __launch_bounds__(256) void mid_k(
    const bf16* __restrict__ t1, const float* __restrict__ wsf, const void* __restrict__ b_fp,
    bf16* __restrict__ u, bf16* __restrict__ xpre, bf16* __restrict__ siluz,
    const int* __restrict__ flagp)
{
  __shared__ short ul[32 * 136];
  const int f = *flagp;
  const int tid = threadIdx.x;
  const int tok0 = blockIdx.x * 32;
  const int lane = tid & 63, m = lane & 15, q = lane >> 4;
  const int w = tid >> 6, mt = w & 1, ng = w >> 1;
  const bf16* WF = (const bf16*)(wsf + OFF_WB) + WB_FP;
  const bf16* WP = (const bf16*)(wsf + OFF_WB) + WB_PR;
  {  // phase 1: K=128, N=128, A from global t1
    bf16x8 a[4];
    #pragma unroll
    for (int kk = 0; kk < 4; ++kk)
      a[kk] = *(const bf16x8*)(t1 + (tok0 + mt * 16 + m) * 128 + kk * 32 + q * 8);
    #pragma unroll
    for (int nti = 0; nti < 4; ++nti) {
      int nt = ng * 4 + nti;
      f32x4 acc = {0.f, 0.f, 0.f, 0.f};
      #pragma unroll
      for (int kk = 0; kk < 4; ++kk) {
        bf16x8 b = *(const bf16x8*)(WF + (nt * 16 + m) * 128 + kk * 32 + q * 8);
        acc = __builtin_amdgcn_mfma_f32_16x16x32_bf16(a[kk], b, acc, 0, 0, 0);
      }
      int n = nt * 16 + m;
      float bv = ldin(b_fp, n, f);
      #pragma unroll
      for (int r = 0; r < 4; ++r) {
        bf16 h = f2b(acc[r] + bv);
        ul[(mt * 16 + q * 4 + r) * 136 + n] = shof(h);
        u[(tok0 + mt * 16 + q * 4 + r) * 128 + n] = h;
      }
    }
  }
  __syncthreads();
  {  // phase 2: K=128, N=512, A from LDS u
    bf16x8 a[4];
    #pragma unroll
    for (int kk = 0; kk < 4; ++kk)
      a[kk] = *(const bf16x8*)&ul[(mt * 16 + m) * 136 + kk * 32 + q * 8];
    #pragma unroll
    for (int nti = 0; nti < 16; ++nti) {
      int nt = ng * 16 + nti;
      f32x4 acc = {0.f, 0.f, 0.f, 0.f};
      #pragma unroll
      for (int kk = 0; kk < 4; ++kk) {
        bf16x8 b = *(const bf16x8*)(WP + (nt * 16 + m) * 128 + kk * 32 + q * 8);
        acc = __builtin_amdgcn_mfma_f32_16x16x32_bf16(a[kk], b, acc, 0, 0, 0);
      }
      int n = nt * 16 + m;
      #pragma unroll
      for (int r = 0; r < 4; ++r) {
        int tok = tok0 + mt * 16 + q * 4 + r;
        if (n < 256) xpre[tok * 256 + n] = f2b(acc[r]);
        else         siluz[tok * 256 + (n - 256)] = f2b(silu(acc[r]));
      }
    }
  }
}

// ---------------- conv (depthwise w4 + silu) + x_proj MFMA -> xc, xdbl ----------------
__global__ __launch_bounds__(256) void conv_k(
    const bf16* __restrict__ xpre, const void* __restrict__ cw, const void* __restrict__ cb,
    const float* __restrict__ wsf, bf16* __restrict__ xc, float* __restrict__ xdbl,
    const int* __restrict__ flagp)
{
  __shared__ short xh[35 * 256];
  __shared__ short cs[32 * 264];
  const int f = *flagp;
  const int tid = threadIdx.x;
  const int tok0 = blockIdx.x * 32;
  for (int c = tid; c < 1120; c += 256) {
    int e0 = c * 8;
    int tt = e0 >> 8, i = e0 & 255;
    int gtok = tok0 + tt - 3;
    uint4* dst = (uint4*)(xh + e0);
    if (gtok >= 0) *dst = *(const uint4*)(xpre + gtok * 256 + i);
    else           *dst = make_uint4(0, 0, 0, 0);
  }
  __syncthreads();
  {
    const int ch = tid;
    float cwv[4];
    #pragma unroll
    for (int k = 0; k < 4; ++k) cwv[k] = ldin(cw, ch * 4 + k, f);
    const float cbv = ldin(cb, ch, f);
    for (int t = 0; t < 32; ++t) {
      int l = (tok0 + t) & (SEQ - 1);
      float acc = cbv;
      #pragma unroll
      for (int k = 0; k < 4; ++k)
        if (l + k - 3 >= 0) acc += b2f(((const bf16*)xh)[(t + k) * 256 + ch]) * cwv[k];
      bf16 v = f2b(silu(acc));
      ((bf16*)cs)[t * 264 + ch] = v;
      xc[(tok0 + t) * 256 + ch] = v;
    }
  }
  __syncthreads();
  const int w = tid >> 6;
  if (w < 2) {
    const bf16* Wx = (const bf16*)(wsf + OFF_WB) + WB_XP;
    const int lane = tid & 63, m = lane & 15, quad = lane >> 4;
    f32x4 acc[3] = {{0,0,0,0},{0,0,0,0},{0,0,0,0}};
    #pragma unroll
    for (int k0 = 0; k0 < 256; k0 += 32) {
      bf16x8 af = *(const bf16x8*)&cs[(w * 16 + m) * 264 + k0 + quad * 8];
      #pragma unroll
      for (int nt = 0; nt < 3; ++nt) {
        bf16x8 bfr = *(const bf16x8*)(Wx + (nt * 16 + m) * 256 + k0 + quad * 8);
        acc[nt] = __builtin_amdgcn_mfma_f32_16x16x32_bf16(af, bfr, acc[nt], 0, 0, 0);
      }
    }
    #pragma unroll
    for (int nt = 0; nt < 3; ++nt) {
      int n = nt * 16 + m;
      if (n < 40) {
        #pragma unroll
        for (int r = 0; r < 4; ++r)
          xdbl[(tok0 + w * 16 + quad * 4 + r) * 40 + n] = acc[nt][r];
      }
    }
  }
}

// ---------------- chunked selective scan ----------------
template<bool IS_C>
__global__ __launch_bounds__(256) void scan_k(
    const float* __restrict__ xdbl, const bf16* __restrict__ xc, const bf16* __restrict__ siluz,
    const void* __restrict__ A_log, const void* __restrict__ D_par, const void* __restrict__ dt_b,
    const float* __restrict__ WDT, float* __restrict__ summ, const float* __restrict__ hinit,
    bf16* __restrict__ g, const int* __restrict__ flagp)
{
  const int f = *flagp;
  const int tid = threadIdx.x;
  const int bb = blockIdx.x >> 4, dg = blockIdx.x & 15, c = blockIdx.y;
  const int dl = tid >> 4, s = tid & 15;
  const int j = s;
  const int d_loop = dg * 16 + dl;
  const int d_stg  = dg * 16 + j;
  const int tok_base = bb * SEQ + c * NCH;

  __shared__ float dt_l[NCH * 8];
  __shared__ float dx_l[NCH * 16 * 2];
  __shared__ float bc_l[IS_C ? NCH * 16 * 2 : NCH * 16];
  __shared__ float g_l[IS_C ? NCH * 16 : 1];

  const float Aval = -__expf(ldin(A_log, d_loop * 16 + s, f));
  const float Dp = ldin(D_par, d_loop, f);
  const float dtb_j = ldin(dt_b, d_stg, f);
  float wdt[8];
  #pragma unroll
  for (int r = 0; r < 8; ++r) wdt[r] = WDT[r * 256 + d_stg];

  const int sidx = (blockIdx.x * NCHUNK + c) * 256 + tid;
  float h = IS_C ? hinit[sidx] : 0.f;
  float sdlt = 0.f;

  for (int e2 = tid; e2 < NCH * 8; e2 += 256)
    dt_l[e2] = xdbl[(tok_base + (e2 >> 3)) * 40 + (e2 & 7)];
  #pragma unroll
  for (int k = 0; k < 4; ++k) {
    int e = tid + k * 256;
    int t = e >> 4;
    int tok = tok_base + t;
    float B = xdbl[tok * 40 + 8 + j];
    if (IS_C) {
      bc_l[e * 2 + 0] = B;
      bc_l[e * 2 + 1] = xdbl[tok * 40 + 24 + j];
    } else bc_l[e] = B;
  }
  __syncthreads();
  #pragma unroll
  for (int k = 0; k < 4; ++k) {
    int e = tid + k * 256;
    int t = e >> 4;
    float a = dtb_j;
    #pragma unroll
    for (int r = 0; r < 8; ++r) a = fmaf(dt_l[t * 8 + r], wdt[r], a);
    float xcv = b2f(xc[(tok_base + t) * 256 + d_stg]);
    *(float2*)(dx_l + e * 2) = make_float2(softplus(a), xcv);
  }
  __syncthreads();

  #pragma unroll 8
  for (int t = 0; t < NCH; ++t) {
    float2 dx = *(const float2*)(dx_l + (t * 16 + dl) * 2);
    float dlt = dx.x, xcv = dx.y;
    float dA = __expf(dlt * Aval);
    float du = dlt * xcv;
    if (!IS_C) sdlt += dlt;
    if (IS_C) {
      float2 bc = *(const float2*)(bc_l + (t * 16 + s) * 2);
      h = fmaf(dA, h, du * bc.x);
      float p = h * bc.y;
      p = dpp_add<0x121>(p);
      p = dpp_add<0x122>(p);
      p = dpp_add<0x124>(p);
      p = dpp_add<0x128>(p);
      if (s == 0) g_l[t * 16 + dl] = p + xcv * Dp;
    } else {
      h = fmaf(dA, h, du * bc_l[t * 16 + s]);
    }
  }
  if (IS_C) {
    __syncthreads();
    #pragma unroll
    for (int k = 0; k < 4; ++k) {
      int e = tid + k * 256;
      int t = e >> 4;
      int tok = tok_base + t;
      g[tok * 256 + d_stg] = f2b(g_l[e] * b2f(siluz[tok * 256 + d_stg]));
    }
  } else {
    *(float2*)(summ + sidx * 2) = make_float2(__expf(Aval * sdlt), h);
  }
}

// phase B: exclusive scan over chunk summaries, 8-deep load batching (latency fix)
__global__ __launch_bounds__(256) void scanB_k(const float* __restrict__ summ, float* __restrict__ hinit) {
  int bx = blockIdx.x, qq = threadIdx.x;
  float h = 0.f;
  for (int c0 = 0; c0 < NCHUNK; c0 += 8) {
    float2 sv[8];
    #pragma unroll
    for (int k = 0; k < 8; ++k)
      sv[k] = *(const float2*)(summ + ((bx * NCHUNK + c0 + k) * 256 + qq) * 2);
    #pragma unroll
    for (int k = 0; k < 8; ++k) {
      hinit[(bx * NCHUNK + c0 + k) * 256 + qq] = h;
      h = fmaf(sv[k].x, h, sv[k].y);
    }
  }
}

// ---------------- back: m = g@Wmo^T (LDS) ; rms2+u, gate wsw ; @Wop^T + b + resid ----------------
// grid NTOK/32. waves: mt=w&1, ng=w>>1.
__global__ __launch_bounds__(256) void back_k(
    const bf16* __restrict__ g, const float* __restrict__ wsf, const void* __restrict__ w2,
    const bf16* __restrict__ u, const bf16* __restrict__ wsw, const void* __restrict__ b_op,
    const void* __restrict__ x, void* __restrict__ out, const int* __restrict__ flagp)
{
  __shared__ short ms[32 * 136];
  const int f = *flagp;
  const int tid = threadIdx.x;
  const int tok0 = blockIdx.x * 32;
  const int lane = tid & 63, m = lane & 15, q = lane >> 4;
  const int w = tid >> 6, mt = w & 1, ng = w >> 1;
  const bf16* WM = (const bf16*)(wsf + OFF_WB) + WB_MO;
  const bf16* WO = (const bf16*)(wsf + OFF_WB) + WB_OP;
  {  // phase 1: m = g@Wmo^T  (K=256, N=128), A from global g
    bf16x8 a[8];
    #pragma unroll
    for (int kk = 0; kk < 8; ++kk)
      a[kk] = *(const bf16x8*)(g + (tok0 + mt * 16 + m) * 256 + kk * 32 + q * 8);
    #pragma unroll
    for (int nti = 0; nti < 4; ++nti) {
      int nt = ng * 4 + nti;
      f32x4 acc = {0.f, 0.f, 0.f, 0.f};
      #pragma unroll
      for (int kk = 0; kk < 8; ++kk) {
        bf16x8 b = *(const bf16x8*)(WM + (nt * 16 + m) * 256 + kk * 32 + q * 8);
        acc = __builtin_amdgcn_mfma_f32_16x16x32_bf16(a[kk], b, acc, 0, 0, 0);
      }
      int n = nt * 16 + m;
      #pragma unroll
      for (int r = 0; r < 4; ++r)
        ms[(mt * 16 + q * 4 + r) * 136 + n] = shof(f2b(acc[r]));
    }
  }
  __syncthreads();
  {  // rms2 + u residual + wsw gate (8 threads/token, 16 ch each)
    const int token = tid >> 3, r = tid & 7;
    float mv[16]; float ss = 0.f;
    #pragma unroll
    for (int k = 0; k < 16; ++k) {
      mv[k] = b2f(((const bf16*)ms)[token * 136 + r * 16 + k]);
      ss += mv[k] * mv[k];
    }
    ss += __shfl_xor(ss, 1, 8); ss += __shfl_xor(ss, 2, 8); ss += __shfl_xor(ss, 4, 8);
    float sc = rsqrtf(ss * (1.f / 128.f) + EPS);
    #pragma unroll
    for (int k = 0; k < 16; ++k) {
      int i = r * 16 + k;
      int ga = (tok0 + token) * 128 + i;
      float v = mv[k] * sc * ldin(w2, i, f) + b2f(u[ga]);
      ms[token * 136 + i] = shof(f2b(v * b2f(wsw[ga])));
    }
  }
  __syncthreads();
  {  // phase 2: out = ms@Wop^T + b_op + resid  (K=128, N=64)
    bf16x8 a[4];
    #pragma unroll
    for (int kk = 0; kk < 4; ++kk)
      a[kk] = *(const bf16x8*)&ms[(mt * 16 + m) * 136 + kk * 32 + q * 8];
    #pragma unroll
    for (int nti = 0; nti < 2; ++nti) {
      int nt = ng * 2 + nti;
      f32x4 acc = {0.f, 0.f, 0.f, 0.f};
      #pragma unroll
      for (int kk = 0; kk < 4; ++kk) {
        bf16x8 b = *(const bf16x8*)(WO + (nt * 16 + m) * 128 + kk * 32 + q * 8);
        acc = __builtin_amdgcn_mfma_f32_16x16x32_bf16(a[kk], b, acc, 0, 0, 0);
      }
      int n = nt * 16 + m;
      float bv = ldin(b_op, n, f);
      #pragma unroll
      for (int r = 0; r < 4; ++r) {
        int token = tok0 + mt * 16 + q * 4 + r;
        float v = acc[r] + bv + ldin(x, token * 64 + n, f);
        if (f) ((float*)out)[token * 64 + n] = v;
        else   ((bf16*)out)[token * 64 + n] = f2b(v);
      }
    }
  }
}

// ---------------- launch ----------------
extern "C" void kernel_launch(void* const* d_in, const int* in_sizes, int n_in,
                              void* d_out, int out_size, void* d_ws, size_t ws_size,
                              hipStream_t stream) {
  (void)in_sizes; (void)n_in; (void)out_size; (void)ws_size;
  const void* x        = d_in[0];
  const void* w_norm1  = d_in[1];
  const void* w_norm2  = d_in[2];
  const void* W_ip     = d_in[3];
  const void* b_ip     = d_in[4];
  const void* W_fp     = d_in[5];
  const void* b_fp     = d_in[6];
  const void* W_wp     = d_in[7];
  const void* b_wp     = d_in[8];
  const void* W_op     = d_in[9];
  const void* b_op     = d_in[10];
  const void* in_proj  = d_in[11];
  const void* conv_w   = d_in[12];
  const void* conv_b   = d_in[13];
  const void* x_proj   = d_in[14];
  const void* dt_projw = d_in[15];
  const void* dt_projb = d_in[16];
  const void* A_log    = d_in[17];
  const void* D_par    = d_in[18];
  const void* mo_w     = d_in[19];

  float* wsf    = (float*)d_ws;
  float* xdbl   = wsf + OFF_XDBL;
  bf16*  t1_b   = (bf16*)(wsf + OFF_R1);
  float* hin    = wsf + OFF_R1;
  bf16*  wsw_b  = (bf16*)(wsf + OFF_WSW);
  bf16*  u_b    = (bf16*)(wsf + OFF_U);
  bf16*  xpre_b = (bf16*)(wsf + OFF_R2);
  float* summ   = wsf + OFF_R2;
  bf16*  siluz_b= (bf16*)(wsf + OFF_SILUZ);
  bf16*  xc_b   = (bf16*)(wsf + OFF_XC);
  bf16*  g_b    = (bf16*)(wsf + OFF_G);
  int*   flagp  = (int*)(wsf + OFF_FLAG);

  prep_k<<<dim3(592), dim3(256), 0, stream>>>(W_ip, W_wp, W_fp, in_proj, mo_w, W_op,
                                              x_proj, dt_projw, x, wsf, flagp);
  front_k<<<dim3(NTOK / 32), dim3(256), 0, stream>>>(x, w_norm1, wsf, b_ip, b_wp, t1_b, wsw_b, flagp);
  mid_k<<<dim3(NTOK / 32), dim3(256), 0, stream>>>(t1_b, wsf, b_fp, u_b, xpre_b, siluz_b, flagp);
  conv_k<<<dim3(NTOK / 32), dim3(256), 0, stream>>>(xpre_b, conv_w, conv_b, wsf, xc_b, xdbl, flagp);
  scan_k<false><<<dim3(64, NCHUNK), dim3(256), 0, stream>>>(xdbl, xc_b, siluz_b, A_log, D_par,
                                                            dt_projb, wsf + OFF_WDT, summ, hin, g_b, flagp);
  scanB_k<<<dim3(64), dim3(256), 0, stream>>>(summ, hin);
  scan_k<true><<<dim3(64, NCHUNK), dim3(256), 0, stream>>>(xdbl, xc_b, siluz_b, A_log, D_par,
                                                           dt_projb, wsf + OFF_WDT, summ, hin, g_b, flagp);
  back_k<<<dim3(NTOK / 32), dim3(256), 0, stream>>>(g_b, wsf, w_norm2, u_b, wsw_b, b_op, x, d_out, flagp);
}

// Round 7
// 209.426 us; speedup vs baseline: 2.7778x; 1.1553x over previous
//
#include <hip/hip_runtime.h>
#include <hip/hip_bf16.h>

typedef __hip_bfloat16 bf16;
typedef __attribute__((ext_vector_type(8))) short bf16x8;
typedef __attribute__((ext_vector_type(4))) float f32x4;
#define DEV __device__ __forceinline__

constexpr int SEQ  = 4096;
constexpr int NB   = 4;
constexpr int NTOK = NB * SEQ;          // 16384 tokens
constexpr float EPS = 1e-5f;
constexpr int NCH = 64;                 // scan chunk length
constexpr int NCHUNK = SEQ / NCH;       // 64 chunks/seq
constexpr float LOG2E = 1.44269504f;

// ---------------- workspace layout (float offsets) ----------------
constexpr int OFF_WDT  = 0;                    // f32 [8][256] dt_proj^T
constexpr int OFF_WB   = 2048;                 // bf16 weight area (151552 shorts)
constexpr int WB_IP = 0;                       // [128][64]
constexpr int WB_WP = 8192;                    // [128][64]
constexpr int WB_FP = 16384;                   // [128][128]
constexpr int WB_PR = 32768;                   // [512][128]
constexpr int WB_MO = 98304;                   // [128][256]
constexpr int WB_OP = 131072;                  // [64][128]
constexpr int WB_XP = 139264;                  // [48][256] (40 real + 8 zero rows)
constexpr int WB_TOT = 151552;
constexpr int OFF_XDBL = OFF_WB + WB_TOT / 2;        // f32 [NTOK][40] (655360 f)
constexpr int OFF_R1   = OFF_XDBL + NTOK * 40;       // hinit (1048576 f)
constexpr int OFF_WSW  = OFF_R1   + 1048576;         // bf16 NTOK*128  -> 1048576 f
constexpr int OFF_U    = OFF_WSW  + 1048576;         // bf16 NTOK*128  -> 1048576 f
constexpr int OFF_R2   = OFF_U    + 1048576;         // xpre / summ    (2097152 f)
constexpr int OFF_SILUZ= OFF_R2   + 2097152;         // bf16 NTOK*256  -> 2097152 f
constexpr int OFF_XC   = OFF_SILUZ+ 2097152;         // bf16 NTOK*256
constexpr int OFF_G    = OFF_XC   + 2097152;         // bf16 NTOK*256
constexpr int OFF_FLAG = OFF_G    + 2097152;         // int dtype flag

DEV float b2f(bf16 x) { return __bfloat162float(x); }
DEV bf16 f2b(float x) { return __float2bfloat16(x); }
DEV short shof(bf16 h) { short s; __builtin_memcpy(&s, &h, 2); return s; }
DEV float ldin(const void* p, int i, int f) {
  return f ? ((const float*)p)[i] : b2f(((const bf16*)p)[i]);
}
DEV unsigned pack2(float a, float b) {
  bf16 ha = f2b(a), hb = f2b(b);
  unsigned short ua, ub;
  __builtin_memcpy(&ua, &ha, 2); __builtin_memcpy(&ub, &hb, 2);
  return (unsigned)ua | ((unsigned)ub << 16);
}
DEV float lo16f(unsigned u) { return __int_as_float((int)(u << 16)); }
DEV float hi16f(unsigned u) { return __int_as_float((int)(u & 0xffff0000u)); }
template<int CTRL>
DEV float dpp_add(float v) {
  int r = __builtin_amdgcn_update_dpp(0, __float_as_int(v), CTRL, 0xF, 0xF, false);
  return v + __int_as_float(r);
}
DEV float exp2f_fast(float a) { return __builtin_amdgcn_exp2f(a); }
// softplus(a) = log(1+e^a); cheap form via exp2/log
DEV float softplus(float a) {
  return (a > 20.f) ? a : __logf(1.f + exp2f_fast(a * LOG2E));
}
DEV float silu(float a) { return a / (1.f + __expf(-a)); }

// ---------------- prep: inline dtype detect + bf16 weight copies + WDT f32 ----------------
DEV void cpw(int e, int base, int count, const void* __restrict__ src,
             bf16* __restrict__ wb, int f) {
  int r = e - base;
  if (r >= 0 && r < count) wb[base + r] = f2b(ldin(src, r, f));
}
__global__ __launch_bounds__(256) void prep_k(
    const void* __restrict__ w_ip, const void* __restrict__ w_wp, const void* __restrict__ w_fp,
    const void* __restrict__ w_pr, const void* __restrict__ w_mo, const void* __restrict__ w_op,
    const void* __restrict__ w_x,  const void* __restrict__ w_dt,
    const void* __restrict__ x, float* __restrict__ wsf, int* __restrict__ flagp)
{
  __shared__ int cnt;
  if (threadIdx.x == 0) cnt = 0;
  __syncthreads();
  {
    float v = b2f(((const bf16*)x)[threadIdx.x]);
    int ok = (v == v) && fabsf(v) > 1e-4f && fabsf(v) < 100.f;
    atomicAdd(&cnt, ok);
  }
  __syncthreads();
  int f = (cnt > 204) ? 0 : 1;
  if (blockIdx.x == 0 && threadIdx.x == 0) *flagp = f;

  int e = blockIdx.x * 256 + threadIdx.x;   // 592*256 covers 151552
  bf16* wb = (bf16*)(wsf + OFF_WB);
  cpw(e, WB_IP, 8192,  w_ip, wb, f);
  cpw(e, WB_WP, 8192,  w_wp, wb, f);
  cpw(e, WB_FP, 16384, w_fp, wb, f);
  cpw(e, WB_PR, 65536, w_pr, wb, f);
  cpw(e, WB_MO, 32768, w_mo, wb, f);
  cpw(e, WB_OP, 8192,  w_op, wb, f);
  {
    int r = e - WB_XP;
    if (r >= 0 && r < 12288) wb[WB_XP + r] = (r < 10240) ? f2b(ldin(w_x, r, f)) : f2b(0.f);
  }
  if (e < 2048) {
    int r = e >> 8, d = e & 255;
    wsf[OFF_WDT + e] = ldin(w_dt, d * 8 + r, f);
  }
}

// ---------------- fm: rms1 + ip/wp GEMMs + fp GEMM + in_proj GEMM, t1/u via LDS ----------------
// grid NTOK/32. Block = 32 tokens, 4 waves; each wave covers BOTH 16-token m-tiles.
__global__ __launch_bounds__(256) void fm_k(
    const void* __restrict__ x, const void* __restrict__ w1, const float* __restrict__ wsf,
    const void* __restrict__ b_ip, const void* __restrict__ b_wp, const void* __restrict__ b_fp,
    bf16* __restrict__ wsw, bf16* __restrict__ u, bf16* __restrict__ xpre,
    bf16* __restrict__ siluz, const int* __restrict__ flagp)
{
  __shared__ short xn[32 * 72];
  __shared__ short t1[32 * 136];
  __shared__ short ul[32 * 136];
  const int f = *flagp;
  const int tid = threadIdx.x;
  const int tok0 = blockIdx.x * 32;
  {  // rms1: 8 threads/token, 8 ch each
    const int token = tid >> 3, r = tid & 7;
    float v[8]; float ss = 0.f;
    #pragma unroll
    for (int k = 0; k < 8; ++k) {
      v[k] = ldin(x, (tok0 + token) * 64 + r * 8 + k, f);
      ss += v[k] * v[k];
    }
    ss += __shfl_xor(ss, 1, 8); ss += __shfl_xor(ss, 2, 8); ss += __shfl_xor(ss, 4, 8);
    float sc = rsqrtf(ss * (1.f / 64.f) + EPS);
    unsigned* dst = (unsigned*)xn + token * 36 + r * 4;
    #pragma unroll
    for (int k = 0; k < 4; ++k) {
      int i = r * 8 + k * 2;
      dst[k] = pack2(v[k*2] * sc * ldin(w1, i, f), v[k*2+1] * sc * ldin(w1, i + 1, f));
    }
  }
  __syncthreads();
  const int lane = tid & 63, m = lane & 15, q = lane >> 4;
  const int w = tid >> 6;
  {  // GEMM1/1b: K=64, N=128 each. waves 0,1 -> Wip (t1), 2,3 -> Wwp (wsw)
    const int wt = w >> 1, ng = w & 1;
    const bf16* W = (const bf16*)(wsf + OFF_WB) + (wt ? WB_WP : WB_IP);
    const void* bia = wt ? b_wp : b_ip;
    bf16x8 a[2][2];
    #pragma unroll
    for (int mt = 0; mt < 2; ++mt)
      #pragma unroll
      for (int kk = 0; kk < 2; ++kk)
        a[mt][kk] = *(const bf16x8*)&xn[(mt * 16 + m) * 72 + kk * 32 + q * 8];
    #pragma unroll
    for (int nti = 0; nti < 4; ++nti) {
      int nt = ng * 4 + nti;
      int n = nt * 16 + m;
      f32x4 acc[2] = {{0,0,0,0},{0,0,0,0}};
      #pragma unroll
      for (int kk = 0; kk < 2; ++kk) {
        bf16x8 b = *(const bf16x8*)(W + (nt * 16 + m) * 64 + kk * 32 + q * 8);
        #pragma unroll
        for (int mt = 0; mt < 2; ++mt)
          acc[mt] = __builtin_amdgcn_mfma_f32_16x16x32_bf16(a[mt][kk], b, acc[mt], 0, 0, 0);
      }
      float bv = ldin(bia, n, f);
      #pragma unroll
      for (int mt = 0; mt < 2; ++mt)
        #pragma unroll
        for (int r = 0; r < 4; ++r) {
          float v = acc[mt][r] + bv;
          if (wt) wsw[(tok0 + mt * 16 + q * 4 + r) * 128 + n] = f2b(silu(v));
          else    t1[(mt * 16 + q * 4 + r) * 136 + n] = shof(f2b(v));
        }
    }
  }
  __syncthreads();
  {  // GEMM2: u = t1@Wfp^T + b_fp. K=128, N=128; wave w -> nt {2w, 2w+1}
    const bf16* WF = (const bf16*)(wsf + OFF_WB) + WB_FP;
    bf16x8 a[2][4];
    #pragma unroll
    for (int mt = 0; mt < 2; ++mt)
      #pragma unroll
      for (int kk = 0; kk < 4; ++kk)
        a[mt][kk] = *(const bf16x8*)&t1[(mt * 16 + m) * 136 + kk * 32 + q * 8];
    #pragma unroll
    for (int nti = 0; nti < 2; ++nti) {
      int nt = w * 2 + nti;
      int n = nt * 16 + m;
      f32x4 acc[2] = {{0,0,0,0},{0,0,0,0}};
      #pragma unroll
      for (int kk = 0; kk < 4; ++kk) {
        bf16x8 b = *(const bf16x8*)(WF + (nt * 16 + m) * 128 + kk * 32 + q * 8);
        #pragma unroll
        for (int mt = 0; mt < 2; ++mt)
          acc[mt] = __builtin_amdgcn_mfma_f32_16x16x32_bf16(a[mt][kk], b, acc[mt], 0, 0, 0);
      }
      float bv = ldin(b_fp, n, f);
      #pragma unroll
      for (int mt = 0; mt < 2; ++mt)
        #pragma unroll
        for (int r = 0; r < 4; ++r) {
          bf16 h = f2b(acc[mt][r] + bv);
          ul[(mt * 16 + q * 4 + r) * 136 + n] = shof(h);
          u[(tok0 + mt * 16 + q * 4 + r) * 128 + n] = h;
        }
    }
  }
  __syncthreads();
  {  // GEMM3: xz = u@Wpr^T. K=128, N=512; wave w -> nt [8w, 8w+8)
    const bf16* WP = (const bf16*)(wsf + OFF_WB) + WB_PR;
    bf16x8 a[2][4];
    #pragma unroll
    for (int mt = 0; mt < 2; ++mt)
      #pragma unroll
      for (int kk = 0; kk < 4; ++kk)
        a[mt][kk] = *(const bf16x8*)&ul[(mt * 16 + m) * 136 + kk * 32 + q * 8];
    #pragma unroll
    for (int nti = 0; nti < 8; ++nti) {
      int nt = w * 8 + nti;
      int n = nt * 16 + m;
      f32x4 acc[2] = {{0,0,0,0},{0,0,0,0}};
      #pragma unroll
      for (int kk = 0; kk < 4; ++kk) {
        bf16x8 b = *(const bf16x8*)(WP + (nt * 16 + m) * 128 + kk * 32 + q * 8);
        #pragma unroll
        for (int mt = 0; mt < 2; ++mt)
          acc[mt] = __builtin_amdgcn_mfma_f32_16x16x32_bf16(a[mt][kk], b, acc[mt], 0, 0, 0);
      }
      #pragma unroll
      for (int mt = 0; mt < 2; ++mt)
        #pragma unroll
        for (int r = 0; r < 4; ++r) {
          int tok = tok0 + mt * 16 + q * 4 + r;
          if (n < 256) xpre[tok * 256 + n] = f2b(acc[mt][r]);
          else         siluz[tok * 256 + (n - 256)] = f2b(silu(acc[mt][r]));
        }
    }
  }
}

// ---------------- conv (depthwise w4 + silu) + x_proj MFMA -> xc, xdbl ----------------
// conv inner: thread = (t-quarter, 4 channels); sliding 11-row window, b64 LDS reads.
__global__ __launch_bounds__(256) void conv_k(
    const bf16* __restrict__ xpre, const void* __restrict__ cw, const void* __restrict__ cb,
    const float* __restrict__ wsf, bf16* __restrict__ xc, float* __restrict__ xdbl,
    const int* __restrict__ flagp)
{
  __shared__ short xh[35 * 256];
  __shared__ short cs[32 * 264];
  const int f = *flagp;
  const int tid = threadIdx.x;
  const int tok0 = blockIdx.x * 32;
  const bool seqstart = (tok0 & (SEQ - 1)) == 0;
  for (int c = tid; c < 1120; c += 256) {
    int e0 = c * 8;
    int tt = e0 >> 8, i = e0 & 255;
    int gtok = tok0 + tt - 3;
    uint4* dst = (uint4*)(xh + e0);
    if (gtok >= 0 && !(seqstart && tt < 3)) *dst = *(const uint4*)(xpre + gtok * 256 + i);
    else                                    *dst = make_uint4(0, 0, 0, 0);
  }
  __syncthreads();
  {
    const int ch0 = (tid & 63) * 4;
    const int t0 = (tid >> 6) * 8;
    float w4[4][4], cb4[4];
    #pragma unroll
    for (int c = 0; c < 4; ++c) {
      cb4[c] = ldin(cb, ch0 + c, f);
      #pragma unroll
      for (int k = 0; k < 4; ++k) w4[c][k] = ldin(cw, (ch0 + c) * 4 + k, f);
    }
    float win[11][4];
    #pragma unroll
    for (int r = 0; r < 11; ++r) {
      uint2 v = *(const uint2*)&xh[(t0 + r) * 256 + ch0];
      win[r][0] = lo16f(v.x); win[r][1] = hi16f(v.x);
      win[r][2] = lo16f(v.y); win[r][3] = hi16f(v.y);
    }
    #pragma unroll
    for (int t = 0; t < 8; ++t) {
      unsigned pk[2];
      #pragma unroll
      for (int cp = 0; cp < 2; ++cp) {
        float o[2];
        #pragma unroll
        for (int ci = 0; ci < 2; ++ci) {
          int c = cp * 2 + ci;
          float acc = cb4[c];
          #pragma unroll
          for (int k = 0; k < 4; ++k) acc = fmaf(win[t + k][c], w4[c][k], acc);
          o[ci] = silu(acc);
        }
        pk[cp] = pack2(o[0], o[1]);
      }
      uint2 pv = make_uint2(pk[0], pk[1]);
      *(uint2*)&cs[(t0 + t) * 264 + ch0] = pv;
      *(uint2*)(xc + (tok0 + t0 + t) * 256 + ch0) = pv;
    }
  }
  __syncthreads();
  const int w = tid >> 6;
  if (w < 2) {
    const bf16* Wx = (const bf16*)(wsf + OFF_WB) + WB_XP;
    const int lane = tid & 63, m = lane & 15, quad = lane >> 4;
    f32x4 acc[3] = {{0,0,0,0},{0,0,0,0},{0,0,0,0}};
    #pragma unroll
    for (int k0 = 0; k0 < 256; k0 += 32) {
      bf16x8 af = *(const bf16x8*)&cs[(w * 16 + m) * 264 + k0 + quad * 8];
      #pragma unroll
      for (int nt = 0; nt < 3; ++nt) {
        bf16x8 bfr = *(const bf16x8*)(Wx + (nt * 16 + m) * 256 + k0 + quad * 8);
        acc[nt] = __builtin_amdgcn_mfma_f32_16x16x32_bf16(af, bfr, acc[nt], 0, 0, 0);
      }
    }
    #pragma unroll
    for (int nt = 0; nt < 3; ++nt) {
      int n = nt * 16 + m;
      if (n < 40) {
        #pragma unroll
        for (int r = 0; r < 4; ++r)
          xdbl[(tok0 + w * 16 + quad * 4 + r) * 40 + n] = acc[nt][r];
      }
    }
  }
}

// ---------------- chunked selective scan (exp2-folded) ----------------
template<bool IS_C>
__global__ __launch_bounds__(256) void scan_k(
    const float* __restrict__ xdbl, const bf16* __restrict__ xc, const bf16* __restrict__ siluz,
    const void* __restrict__ A_log, const void* __restrict__ D_par, const void* __restrict__ dt_b,
    const float* __restrict__ WDT, float* __restrict__ summ, const float* __restrict__ hinit,
    bf16* __restrict__ g, const int* __restrict__ flagp)
{
  const int f = *flagp;
  const int tid = threadIdx.x;
  const int bb = blockIdx.x >> 4, dg = blockIdx.x & 15, c = blockIdx.y;
  const int dl = tid >> 4, s = tid & 15;
  const int j = s;
  const int d_loop = dg * 16 + dl;
  const int d_stg  = dg * 16 + j;
  const int tok_base = bb * SEQ + c * NCH;

  __shared__ float dt_l[NCH * 8];
  __shared__ float dx_l[NCH * 16 * 2];
  __shared__ float bc_l[IS_C ? NCH * 16 * 2 : NCH * 16];
  __shared__ float g_l[IS_C ? NCH * 16 : 1];

  // Aval2 = -exp(A_log) * log2(e): dA = 2^(dlt*Aval2)
  const float Aval2 = -__expf(ldin(A_log, d_loop * 16 + s, f)) * LOG2E;
  const float Dp = ldin(D_par, d_loop, f);
  const float dtb_j = ldin(dt_b, d_stg, f);
  float wdt[8];
  #pragma unroll
  for (int r = 0; r < 8; ++r) wdt[r] = WDT[r * 256 + d_stg];

  const int sidx = (blockIdx.x * NCHUNK + c) * 256 + tid;
  float h = IS_C ? hinit[sidx] : 0.f;
  float sdlt = 0.f;

  for (int e2 = tid * 4; e2 < NCH * 8; e2 += 1024)
    *(float4*)(dt_l + e2) = *(const float4*)(xdbl + (tok_base + (e2 >> 3)) * 40 + (e2 & 7));
  #pragma unroll
  for (int k = 0; k < 4; ++k) {
    int e = tid + k * 256;
    int t = e >> 4;
    int tok = tok_base + t;
    float B = xdbl[tok * 40 + 8 + j];
    if (IS_C) {
      bc_l[e * 2 + 0] = B;
      bc_l[e * 2 + 1] = xdbl[tok * 40 + 24 + j];
    } else bc_l[e] = B;
  }
  __syncthreads();
  #pragma unroll
  for (int k = 0; k < 4; ++k) {
    int e = tid + k * 256;
    int t = e >> 4;
    float a = dtb_j;
    #pragma unroll
    for (int r = 0; r < 8; ++r) a = fmaf(dt_l[t * 8 + r], wdt[r], a);
    float xcv = b2f(xc[(tok_base + t) * 256 + d_stg]);
    *(float2*)(dx_l + e * 2) = make_float2(softplus(a), xcv);
  }
  __syncthreads();

  #pragma unroll 8
  for (int t = 0; t < NCH; ++t) {
    float2 dx = *(const float2*)(dx_l + (t * 16 + dl) * 2);
    float dlt = dx.x, xcv = dx.y;
    float dA = exp2f_fast(dlt * Aval2);
    float du = dlt * xcv;
    if (!IS_C) sdlt += dlt;
    if (IS_C) {
      float2 bc = *(const float2*)(bc_l + (t * 16 + s) * 2);
      h = fmaf(dA, h, du * bc.x);
      float p = h * bc.y;
      p = dpp_add<0x121>(p);
      p = dpp_add<0x122>(p);
      p = dpp_add<0x124>(p);
      p = dpp_add<0x128>(p);
      if (s == 0) g_l[t * 16 + dl] = p + xcv * Dp;
    } else {
      h = fmaf(dA, h, du * bc_l[t * 16 + s]);
    }
  }
  if (IS_C) {
    __syncthreads();
    #pragma unroll
    for (int k = 0; k < 4; ++k) {
      int e = tid + k * 256;
      int t = e >> 4;
      int tok = tok_base + t;
      g[tok * 256 + d_stg] = f2b(g_l[e] * b2f(siluz[tok * 256 + d_stg]));
    }
  } else {
    *(float2*)(summ + sidx * 2) = make_float2(exp2f_fast(Aval2 * sdlt), h);
  }
}

// phase B: exclusive scan over chunk summaries, 8-deep load batching
__global__ __launch_bounds__(256) void scanB_k(const float* __restrict__ summ, float* __restrict__ hinit) {
  int bx = blockIdx.x, qq = threadIdx.x;
  float h = 0.f;
  for (int c0 = 0; c0 < NCHUNK; c0 += 8) {
    float2 sv[8];
    #pragma unroll
    for (int k = 0; k < 8; ++k)
      sv[k] = *(const float2*)(summ + ((bx * NCHUNK + c0 + k) * 256 + qq) * 2);
    #pragma unroll
    for (int k = 0; k < 8; ++k) {
      hinit[(bx * NCHUNK + c0 + k) * 256 + qq] = h;
      h = fmaf(sv[k].x, h, sv[k].y);
    }
  }
}

// ---------------- back: m = g@Wmo^T ; rms2+u, gate wsw ; @Wop^T + b + resid ----------------
// grid NTOK/32. Each wave covers both m-tiles (B-fragment reuse).
__global__ __launch_bounds__(256) void back_k(
    const bf16* __restrict__ g, const float* __restrict__ wsf, const void* __restrict__ w2,
    const bf16* __restrict__ u, const bf16* __restrict__ wsw, const void* __restrict__ b_op,
    const void* __restrict__ x, void* __restrict__ out, const int* __restrict__ flagp)
{
  __shared__ short ms[32 * 136];
  const int f = *flagp;
  const int tid = threadIdx.x;
  const int tok0 = blockIdx.x * 32;
  const int lane = tid & 63, m = lane & 15, q = lane >> 4;
  const int w = tid >> 6;
  const bf16* WM = (const bf16*)(wsf + OFF_WB) + WB_MO;
  const bf16* WO = (const bf16*)(wsf + OFF_WB) + WB_OP;
  {  // phase 1: m = g@Wmo^T (K=256, N=128); wave w -> nt {2w, 2w+1}
    f32x4 acc[2][2] = {{{0,0,0,0},{0,0,0,0}},{{0,0,0,0},{0,0,0,0}}};
    #pragma unroll
    for (int kk = 0; kk < 8; ++kk) {
      bf16x8 a0 = *(const bf16x8*)(g + (tok0 + m) * 256 + kk * 32 + q * 8);
      bf16x8 a1 = *(const bf16x8*)(g + (tok0 + 16 + m) * 256 + kk * 32 + q * 8);
      #pragma unroll
      for (int nti = 0; nti < 2; ++nti) {
        int nt = w * 2 + nti;
        bf16x8 b = *(const bf16x8*)(WM + (nt * 16 + m) * 256 + kk * 32 + q * 8);
        acc[nti][0] = __builtin_amdgcn_mfma_f32_16x16x32_bf16(a0, b, acc[nti][0], 0, 0, 0);
        acc[nti][1] = __builtin_amdgcn_mfma_f32_16x16x32_bf16(a1, b, acc[nti][1], 0, 0, 0);
      }
    }
    #pragma unroll
    for (int nti = 0; nti < 2; ++nti) {
      int n = (w * 2 + nti) * 16 + m;
      #pragma unroll
      for (int mt = 0; mt < 2; ++mt)
        #pragma unroll
        for (int r = 0; r < 4; ++r)
          ms[(mt * 16 + q * 4 + r) * 136 + n] = shof(f2b(acc[nti][mt][r]));
    }
  }
  __syncthreads();
  {  // rms2 + u residual + wsw gate (8 threads/token, 16 ch each)
    const int token = tid >> 3, r = tid & 7;
    float mv[16]; float ss = 0.f;
    #pragma unroll
    for (int k = 0; k < 16; ++k) {
      mv[k] = b2f(((const bf16*)ms)[token * 136 + r * 16 + k]);
      ss += mv[k] * mv[k];
    }
    ss += __shfl_xor(ss, 1, 8); ss += __shfl_xor(ss, 2, 8); ss += __shfl_xor(ss, 4, 8);
    float sc = rsqrtf(ss * (1.f / 128.f) + EPS);
    #pragma unroll
    for (int k = 0; k < 16; ++k) {
      int i = r * 16 + k;
      int ga = (tok0 + token) * 128 + i;
      float v = mv[k] * sc * ldin(w2, i, f) + b2f(u[ga]);
      ms[token * 136 + i] = shof(f2b(v * b2f(wsw[ga])));
    }
  }
  __syncthreads();
  {  // phase 2: out = ms@Wop^T + b_op + resid (K=128, N=64); wave w -> nt w
    bf16x8 a[2][4];
    #pragma unroll
    for (int mt = 0; mt < 2; ++mt)
      #pragma unroll
      for (int kk = 0; kk < 4; ++kk)
        a[mt][kk] = *(const bf16x8*)&ms[(mt * 16 + m) * 136 + kk * 32 + q * 8];
    int nt = w;
    f32x4 acc[2] = {{0,0,0,0},{0,0,0,0}};
    #pragma unroll
    for (int kk = 0; kk < 4; ++kk) {
      bf16x8 b = *(const bf16x8*)(WO + (nt * 16 + m) * 128 + kk * 32 + q * 8);
      #pragma unroll
      for (int mt = 0; mt < 2; ++mt)
        acc[mt] = __builtin_amdgcn_mfma_f32_16x16x32_bf16(a[mt][kk], b, acc[mt], 0, 0, 0);
    }
    int n = nt * 16 + m;
    float bv = ldin(b_op, n, f);
    #pragma unroll
    for (int mt = 0; mt < 2; ++mt)
      #pragma unroll
      for (int r = 0; r < 4; ++r) {
        int token = tok0 + mt * 16 + q * 4 + r;
        float v = acc[mt][r] + bv + ldin(x, token * 64 + n, f);
        if (f) ((float*)out)[token * 64 + n] = v;
        else   ((bf16*)out)[token * 64 + n] = f2b(v);
      }
  }
}

// ---------------- launch ----------------
extern "C" void kernel_launch(void* const* d_in, const int* in_sizes, int n_in,
                              void* d_out, int out_size, void* d_ws, size_t ws_size,
                              hipStream_t stream) {
  (void)in_sizes; (void)n_in; (void)out_size; (void)ws_size;
  const void* x        = d_in[0];
  const void* w_norm1  = d_in[1];
  const void* w_norm2  = d_in[2];
  const void* W_ip     = d_in[3];
  const void* b_ip     = d_in[4];
  const void* W_fp     = d_in[5];
  const void* b_fp     = d_in[6];
  const void* W_wp     = d_in[7];
  const void* b_wp     = d_in[8];
  const void* W_op     = d_in[9];
  const void* b_op     = d_in[10];
  const void* in_proj  = d_in[11];
  const void* conv_w   = d_in[12];
  const void* conv_b   = d_in[13];
  const void* x_proj   = d_in[14];
  const void* dt_projw = d_in[15];
  const void* dt_projb = d_in[16];
  const void* A_log    = d_in[17];
  const void* D_par    = d_in[18];
  const void* mo_w     = d_in[19];

  float* wsf    = (float*)d_ws;
  float* xdbl   = wsf + OFF_XDBL;
  float* hin    = wsf + OFF_R1;
  bf16*  wsw_b  = (bf16*)(wsf + OFF_WSW);
  bf16*  u_b    = (bf16*)(wsf + OFF_U);
  bf16*  xpre_b = (bf16*)(wsf + OFF_R2);
  float* summ   = wsf + OFF_R2;
  bf16*  siluz_b= (bf16*)(wsf + OFF_SILUZ);
  bf16*  xc_b   = (bf16*)(wsf + OFF_XC);
  bf16*  g_b    = (bf16*)(wsf + OFF_G);
  int*   flagp  = (int*)(wsf + OFF_FLAG);

  prep_k<<<dim3(592), dim3(256), 0, stream>>>(W_ip, W_wp, W_fp, in_proj, mo_w, W_op,
                                              x_proj, dt_projw, x, wsf, flagp);
  fm_k<<<dim3(NTOK / 32), dim3(256), 0, stream>>>(x, w_norm1, wsf, b_ip, b_wp, b_fp,
                                                  wsw_b, u_b, xpre_b, siluz_b, flagp);
  conv_k<<<dim3(NTOK / 32), dim3(256), 0, stream>>>(xpre_b, conv_w, conv_b, wsf, xc_b, xdbl, flagp);
  scan_k<false><<<dim3(64, NCHUNK), dim3(256), 0, stream>>>(xdbl, xc_b, siluz_b, A_log, D_par,
                                                            dt_projb, wsf + OFF_WDT, summ, hin, g_b, flagp);
  scanB_k<<<dim3(64), dim3(256), 0, stream>>>(summ, hin);
  scan_k<true><<<dim3(64, NCHUNK), dim3(256), 0, stream>>>(xdbl, xc_b, siluz_b, A_log, D_par,
                                                           dt_projb, wsf + OFF_WDT, summ, hin, g_b, flagp);
  back_k<<<dim3(NTOK / 32), dim3(256), 0, stream>>>(g_b, wsf, w_norm2, u_b, wsw_b, b_op, x, d_out, flagp);
}